// Round 1
// baseline (6679.452 us; speedup 1.0000x reference)
//
#include <hip/hip_runtime.h>
#include <hip/hip_bf16.h>

#define N_NODES 50000
#define N_EDGES 300000
#define DIM 256

// ---------------------------------------------------------------------------
// z = (1 + eps[l]) * h   (elementwise init of aggregation buffer)
// ---------------------------------------------------------------------------
__global__ __launch_bounds__(256) void init_z(const float* __restrict__ h,
                                              float* __restrict__ z,
                                              const float* __restrict__ eps,
                                              int l) {
    float s = 1.0f + eps[l];
    size_t i = (size_t)blockIdx.x * blockDim.x + threadIdx.x;  // float4 index
    const float4* h4 = (const float4*)h;
    float4* z4 = (float4*)z;
    float4 v = h4[i];
    v.x *= s; v.y *= s; v.z *= s; v.w *= s;
    z4[i] = v;
}

// ---------------------------------------------------------------------------
// z[dst[e]] += relu(h[src[e]])   one wave per edge, float4 per lane
// ---------------------------------------------------------------------------
__global__ __launch_bounds__(256) void agg_edges(const float* __restrict__ h,
                                                 const int* __restrict__ src,
                                                 const int* __restrict__ dst,
                                                 float* __restrict__ z, int E) {
    int e = blockIdx.x * 4 + (threadIdx.x >> 6);
    if (e >= E) return;
    int lane = threadIdx.x & 63;
    int s = src[e];
    int d = dst[e];
    const float4* hrow = (const float4*)(h + (size_t)s * DIM);
    float4 v = hrow[lane];
    v.x = fmaxf(v.x, 0.0f);
    v.y = fmaxf(v.y, 0.0f);
    v.z = fmaxf(v.z, 0.0f);
    v.w = fmaxf(v.w, 0.0f);
    float* zrow = z + (size_t)d * DIM + lane * 4;
    atomicAdd(zrow + 0, v.x);
    atomicAdd(zrow + 1, v.y);
    atomicAdd(zrow + 2, v.z);
    atomicAdd(zrow + 3, v.w);
}

// ---------------------------------------------------------------------------
// C[M x 256] = A[M x 256] @ W[256 x 256] + bias
// 64x64 tile per block, 256 threads (16x16), 4x4 microtile, BK=16
// ---------------------------------------------------------------------------
#define BM 64
#define BN 64
#define BK 16

__global__ __launch_bounds__(256) void gemm_f32(const float* __restrict__ A,
                                                const float* __restrict__ W,
                                                const float* __restrict__ bias,
                                                float* __restrict__ C, int M) {
    __shared__ float As[BK][BM + 4];  // +4: keeps 16B alignment for b128 reads
    __shared__ float Bs[BK][BN + 4];

    int tid = threadIdx.x;
    int row0 = blockIdx.y * BM;
    int col0 = blockIdx.x * BN;
    int tx = tid & 15;   // col group
    int ty = tid >> 4;   // row group

    float acc[4][4] = {};

    for (int k0 = 0; k0 < DIM; k0 += BK) {
        // A tile: 64 rows x 16 k  (thread t loads A[row0+ty+16i][k0+tx])
#pragma unroll
        for (int i = 0; i < 4; i++) {
            int r = ty + 16 * i;
            float v = 0.0f;
            if (row0 + r < M) v = A[(size_t)(row0 + r) * DIM + k0 + tx];
            As[tx][r] = v;
        }
        // B tile: 16 k x 64 cols
#pragma unroll
        for (int i = 0; i < 4; i++) {
            int k = (tid >> 6) + 4 * i;
            int c = tid & 63;
            Bs[k][c] = W[(size_t)(k0 + k) * DIM + col0 + c];
        }
        __syncthreads();
#pragma unroll
        for (int k = 0; k < BK; k++) {
            float a[4], b[4];
#pragma unroll
            for (int i = 0; i < 4; i++) a[i] = As[k][ty * 4 + i];
#pragma unroll
            for (int j = 0; j < 4; j++) b[j] = Bs[k][tx * 4 + j];
#pragma unroll
            for (int i = 0; i < 4; i++)
#pragma unroll
                for (int j = 0; j < 4; j++) acc[i][j] += a[i] * b[j];
        }
        __syncthreads();
    }

#pragma unroll
    for (int i = 0; i < 4; i++) {
        int r = row0 + ty * 4 + i;
        if (r < M) {
#pragma unroll
            for (int j = 0; j < 4; j++) {
                int c = col0 + tx * 4 + j;
                C[(size_t)r * DIM + c] = acc[i][j] + bias[c];
            }
        }
    }
}

// ---------------------------------------------------------------------------
// BN stats: per-column sum / sumsq over N rows (block partial + atomics)
// Each block: 64 rows, thread d accumulates column d.
// ---------------------------------------------------------------------------
__global__ __launch_bounds__(256) void bn_stats(const float* __restrict__ Z,
                                                float* __restrict__ stats,
                                                int n) {
    int d = threadIdx.x;
    int r0 = blockIdx.x * 64;
    float s = 0.0f, sq = 0.0f;
    for (int r = r0; r < r0 + 64; r++) {
        if (r < n) {
            float v = Z[(size_t)r * DIM + d];
            s += v;
            sq += v * v;
        }
    }
    atomicAdd(&stats[d], s);
    atomicAdd(&stats[DIM + d], sq);
}

// ---------------------------------------------------------------------------
// Finalize: scale[d] = g*rsqrt(var+1e-5), shift[d] = beta - mean*scale
// ---------------------------------------------------------------------------
__global__ __launch_bounds__(256) void bn_finalize(const float* __restrict__ stats,
                                                   const float* __restrict__ g,
                                                   const float* __restrict__ beta,
                                                   float* __restrict__ scsh,
                                                   int n) {
    int d = threadIdx.x;
    float invn = 1.0f / (float)n;
    float mean = stats[d] * invn;
    float var = stats[DIM + d] * invn - mean * mean;
    float inv = rsqrtf(var + 1e-5f);
    float scale = g[d] * inv;
    scsh[d] = scale;
    scsh[DIM + d] = beta[d] - mean * scale;
}

// ---------------------------------------------------------------------------
// out = (relu?) (in * scale[col] + shift[col])
// ---------------------------------------------------------------------------
__global__ __launch_bounds__(256) void bn_apply(const float* __restrict__ in,
                                                float* __restrict__ out,
                                                const float* __restrict__ scsh,
                                                int do_relu) {
    size_t i = (size_t)blockIdx.x * blockDim.x + threadIdx.x;  // float4 index
    int c4 = (int)(i & 63);  // 64 float4 per row
    const float4* sc4 = (const float4*)scsh;
    const float4* sh4 = (const float4*)(scsh + DIM);
    float4 sc = sc4[c4];
    float4 sh = sh4[c4];
    float4 v = ((const float4*)in)[i];
    v.x = v.x * sc.x + sh.x;
    v.y = v.y * sc.y + sh.y;
    v.z = v.z * sc.z + sh.z;
    v.w = v.w * sc.w + sh.w;
    if (do_relu) {
        v.x = fmaxf(v.x, 0.0f);
        v.y = fmaxf(v.y, 0.0f);
        v.z = fmaxf(v.z, 0.0f);
        v.w = fmaxf(v.w, 0.0f);
    }
    ((float4*)out)[i] = v;
}

// ---------------------------------------------------------------------------
extern "C" void kernel_launch(void* const* d_in, const int* in_sizes, int n_in,
                              void* d_out, int out_size, void* d_ws, size_t ws_size,
                              hipStream_t stream) {
    (void)in_sizes; (void)n_in; (void)out_size; (void)ws_size;
    const float* x   = (const float*)d_in[0];
    const int*   src = (const int*)d_in[1];
    const int*   dst = (const int*)d_in[2];
    const float* W1  = (const float*)d_in[3];
    const float* b1  = (const float*)d_in[4];
    const float* g1  = (const float*)d_in[5];
    const float* bt1 = (const float*)d_in[6];
    const float* W2  = (const float*)d_in[7];
    const float* b2  = (const float*)d_in[8];
    const float* eps = (const float*)d_in[9];
    const float* bng = (const float*)d_in[10];
    const float* bnb = (const float*)d_in[11];
    float* out = (float*)d_out;

    const int N = N_NODES, E = N_EDGES, D = DIM;
    size_t ND = (size_t)N * D;
    float* bufA  = (float*)d_ws;
    float* bufB  = bufA + ND;
    float* stats = bufB + ND;      // 2*D floats
    float* scsh  = stats + 2 * D;  // 2*D floats

    const int ELEM4_BLOCKS = (int)(ND / 4 / 256);     // 12500, exact
    const int AGG_BLOCKS   = (E + 3) / 4;             // 75000
    const int GEMM_Y       = (N + BM - 1) / BM;       // 782
    const int STAT_BLOCKS  = (N + 63) / 64;           // 782

    for (int l = 0; l < 5; l++) {
        const float* hin = (l == 0) ? x : ((l & 1) ? bufA : bufB);
        float* zb = (l & 1) ? bufB : bufA;
        float* tb = (l & 1) ? bufA : bufB;

        // GINConv aggregation: z = (1+eps)*h + scatter_sum(relu(h[src]) -> dst)
        init_z<<<ELEM4_BLOCKS, 256, 0, stream>>>(hin, zb, eps, l);
        agg_edges<<<AGG_BLOCKS, 256, 0, stream>>>(hin, src, dst, zb, E);

        // t = z @ W1 + b1
        gemm_f32<<<dim3(4, GEMM_Y), 256, 0, stream>>>(
            zb, W1 + (size_t)l * D * D, b1 + (size_t)l * D, tb, N);

        // BN1 + relu (in place on t)
        hipMemsetAsync(stats, 0, 2 * D * sizeof(float), stream);
        bn_stats<<<STAT_BLOCKS, 256, 0, stream>>>(tb, stats, N);
        bn_finalize<<<1, 256, 0, stream>>>(stats, g1 + (size_t)l * D,
                                           bt1 + (size_t)l * D, scsh, N);
        bn_apply<<<ELEM4_BLOCKS, 256, 0, stream>>>(tb, tb, scsh, 1);

        // z = t @ W2 + b2  (overwrites zb; zb holds h_next after BN2)
        gemm_f32<<<dim3(4, GEMM_Y), 256, 0, stream>>>(
            tb, W2 + (size_t)l * D * D, b2 + (size_t)l * D, zb, N);

        // BN2 (+ relu except last layer)
        hipMemsetAsync(stats, 0, 2 * D * sizeof(float), stream);
        bn_stats<<<STAT_BLOCKS, 256, 0, stream>>>(zb, stats, N);
        bn_finalize<<<1, 256, 0, stream>>>(stats, bng + (size_t)l * D,
                                           bnb + (size_t)l * D, scsh, N);
        float* outp = (l == 4) ? out : zb;
        bn_apply<<<ELEM4_BLOCKS, 256, 0, stream>>>(zb, outp, scsh, (l < 4) ? 1 : 0);
    }
}

// Round 2
// 2060.411 us; speedup vs baseline: 3.2418x; 3.2418x over previous
//
#include <hip/hip_runtime.h>
#include <hip/hip_bf16.h>

#define N_NODES 50000
#define N_EDGES 300000
#define DIM 256

// ---------------------------------------------------------------------------
// CSR build step 1: histogram of dst
// ---------------------------------------------------------------------------
__global__ __launch_bounds__(256) void hist_dst(const int* __restrict__ dst,
                                                int* __restrict__ deg, int E) {
    int e = blockIdx.x * blockDim.x + threadIdx.x;
    if (e < E) atomicAdd(&deg[dst[e]], 1);
}

// ---------------------------------------------------------------------------
// CSR build step 2: single-block exclusive scan over deg[0..n) -> ptr[0..n]
// Also re-initializes deg[i] = ptr[i] so it can serve as the scatter cursor.
// ---------------------------------------------------------------------------
__global__ __launch_bounds__(1024) void scan_deg(int* __restrict__ deg,
                                                 int* __restrict__ ptr, int n) {
    __shared__ int buf[1024];
    __shared__ int carry_s;
    int tid = threadIdx.x;
    if (tid == 0) carry_s = 0;
    __syncthreads();
    for (int base = 0; base < n; base += 1024) {
        int i = base + tid;
        int v = (i < n) ? deg[i] : 0;
        buf[tid] = v;
        __syncthreads();
        // Hillis-Steele inclusive scan
        for (int off = 1; off < 1024; off <<= 1) {
            int t = (tid >= off) ? buf[tid - off] : 0;
            __syncthreads();
            buf[tid] += t;
            __syncthreads();
        }
        int incl = buf[tid];
        int excl = incl - v;
        int c = carry_s;
        if (i < n) { ptr[i] = c + excl; deg[i] = c + excl; }
        __syncthreads();
        if (tid == 1023) carry_s += incl;
        __syncthreads();
    }
    if (tid == 0) ptr[n] = carry_s;
}

// ---------------------------------------------------------------------------
// CSR build step 3: counting-sort scatter. srcbuf[slot] = src[e], bucketed by dst.
// deg[] holds the running cursor (initialized to ptr[] by scan_deg).
// ---------------------------------------------------------------------------
__global__ __launch_bounds__(256) void scatter_src(const int* __restrict__ src,
                                                   const int* __restrict__ dst,
                                                   int* __restrict__ cursor,
                                                   int* __restrict__ srcbuf, int E) {
    int e = blockIdx.x * blockDim.x + threadIdx.x;
    if (e < E) {
        int pos = atomicAdd(&cursor[dst[e]], 1);
        srcbuf[pos] = src[e];
    }
}

// ---------------------------------------------------------------------------
// Gather aggregation: z[n] = (1+eps)*h[n] + sum_{e in CSR(n)} relu(h[srcbuf[e]])
// One wave per node, float4 per lane (64 lanes * 4 = 256 = DIM).
// ---------------------------------------------------------------------------
__global__ __launch_bounds__(256) void gather_agg(const float* __restrict__ h,
                                                  const int* __restrict__ ptr,
                                                  const int* __restrict__ srcbuf,
                                                  float* __restrict__ z,
                                                  const float* __restrict__ eps,
                                                  int l) {
    int node = blockIdx.x * 4 + (threadIdx.x >> 6);
    if (node >= N_NODES) return;
    int lane = threadIdx.x & 63;
    int beg = ptr[node];
    int end = ptr[node + 1];
    float s = 1.0f + eps[l];
    float4 acc = ((const float4*)(h + (size_t)node * DIM))[lane];
    acc.x *= s; acc.y *= s; acc.z *= s; acc.w *= s;
    for (int e = beg; e < end; e++) {
        int sn = srcbuf[e];
        float4 v = ((const float4*)(h + (size_t)sn * DIM))[lane];
        acc.x += fmaxf(v.x, 0.0f);
        acc.y += fmaxf(v.y, 0.0f);
        acc.z += fmaxf(v.z, 0.0f);
        acc.w += fmaxf(v.w, 0.0f);
    }
    ((float4*)(z + (size_t)node * DIM))[lane] = acc;
}

// ---------------------------------------------------------------------------
// C[M x 256] = A[M x 256] @ W[256 x 256] + bias
// 64x64 tile per block, 256 threads (16x16), 4x4 microtile, BK=16
// ---------------------------------------------------------------------------
#define BM 64
#define BN 64
#define BK 16

__global__ __launch_bounds__(256) void gemm_f32(const float* __restrict__ A,
                                                const float* __restrict__ W,
                                                const float* __restrict__ bias,
                                                float* __restrict__ C, int M) {
    __shared__ float As[BK][BM + 4];
    __shared__ float Bs[BK][BN + 4];

    int tid = threadIdx.x;
    int row0 = blockIdx.y * BM;
    int col0 = blockIdx.x * BN;
    int tx = tid & 15;
    int ty = tid >> 4;

    float acc[4][4] = {};

    for (int k0 = 0; k0 < DIM; k0 += BK) {
#pragma unroll
        for (int i = 0; i < 4; i++) {
            int r = ty + 16 * i;
            float v = 0.0f;
            if (row0 + r < M) v = A[(size_t)(row0 + r) * DIM + k0 + tx];
            As[tx][r] = v;
        }
#pragma unroll
        for (int i = 0; i < 4; i++) {
            int k = (tid >> 6) + 4 * i;
            int c = tid & 63;
            Bs[k][c] = W[(size_t)(k0 + k) * DIM + col0 + c];
        }
        __syncthreads();
#pragma unroll
        for (int k = 0; k < BK; k++) {
            float a[4], b[4];
#pragma unroll
            for (int i = 0; i < 4; i++) a[i] = As[k][ty * 4 + i];
#pragma unroll
            for (int j = 0; j < 4; j++) b[j] = Bs[k][tx * 4 + j];
#pragma unroll
            for (int i = 0; i < 4; i++)
#pragma unroll
                for (int j = 0; j < 4; j++) acc[i][j] += a[i] * b[j];
        }
        __syncthreads();
    }

#pragma unroll
    for (int i = 0; i < 4; i++) {
        int r = row0 + ty * 4 + i;
        if (r < M) {
#pragma unroll
            for (int j = 0; j < 4; j++) {
                int c = col0 + tx * 4 + j;
                C[(size_t)r * DIM + c] = acc[i][j] + bias[c];
            }
        }
    }
}

// ---------------------------------------------------------------------------
// BN stats: per-column sum / sumsq over N rows (block partial + atomics)
// ---------------------------------------------------------------------------
__global__ __launch_bounds__(256) void bn_stats(const float* __restrict__ Z,
                                                float* __restrict__ stats,
                                                int n) {
    int d = threadIdx.x;
    int r0 = blockIdx.x * 64;
    float s = 0.0f, sq = 0.0f;
    for (int r = r0; r < r0 + 64; r++) {
        if (r < n) {
            float v = Z[(size_t)r * DIM + d];
            s += v;
            sq += v * v;
        }
    }
    atomicAdd(&stats[d], s);
    atomicAdd(&stats[DIM + d], sq);
}

// ---------------------------------------------------------------------------
__global__ __launch_bounds__(256) void bn_finalize(const float* __restrict__ stats,
                                                   const float* __restrict__ g,
                                                   const float* __restrict__ beta,
                                                   float* __restrict__ scsh,
                                                   int n) {
    int d = threadIdx.x;
    float invn = 1.0f / (float)n;
    float mean = stats[d] * invn;
    float var = stats[DIM + d] * invn - mean * mean;
    float inv = rsqrtf(var + 1e-5f);
    float scale = g[d] * inv;
    scsh[d] = scale;
    scsh[DIM + d] = beta[d] - mean * scale;
}

// ---------------------------------------------------------------------------
__global__ __launch_bounds__(256) void bn_apply(const float* __restrict__ in,
                                                float* __restrict__ out,
                                                const float* __restrict__ scsh,
                                                int do_relu) {
    size_t i = (size_t)blockIdx.x * blockDim.x + threadIdx.x;
    int c4 = (int)(i & 63);
    const float4* sc4 = (const float4*)scsh;
    const float4* sh4 = (const float4*)(scsh + DIM);
    float4 sc = sc4[c4];
    float4 sh = sh4[c4];
    float4 v = ((const float4*)in)[i];
    v.x = v.x * sc.x + sh.x;
    v.y = v.y * sc.y + sh.y;
    v.z = v.z * sc.z + sh.z;
    v.w = v.w * sc.w + sh.w;
    if (do_relu) {
        v.x = fmaxf(v.x, 0.0f);
        v.y = fmaxf(v.y, 0.0f);
        v.z = fmaxf(v.z, 0.0f);
        v.w = fmaxf(v.w, 0.0f);
    }
    ((float4*)out)[i] = v;
}

// ---------------------------------------------------------------------------
extern "C" void kernel_launch(void* const* d_in, const int* in_sizes, int n_in,
                              void* d_out, int out_size, void* d_ws, size_t ws_size,
                              hipStream_t stream) {
    (void)in_sizes; (void)n_in; (void)out_size; (void)ws_size;
    const float* x   = (const float*)d_in[0];
    const int*   src = (const int*)d_in[1];
    const int*   dst = (const int*)d_in[2];
    const float* W1  = (const float*)d_in[3];
    const float* b1  = (const float*)d_in[4];
    const float* g1  = (const float*)d_in[5];
    const float* bt1 = (const float*)d_in[6];
    const float* W2  = (const float*)d_in[7];
    const float* b2  = (const float*)d_in[8];
    const float* eps = (const float*)d_in[9];
    const float* bng = (const float*)d_in[10];
    const float* bnb = (const float*)d_in[11];
    float* out = (float*)d_out;

    const int N = N_NODES, E = N_EDGES, D = DIM;
    size_t ND = (size_t)N * D;
    float* bufA  = (float*)d_ws;
    float* bufB  = bufA + ND;
    float* stats = bufB + ND;       // 2*D floats
    float* scsh  = stats + 2 * D;   // 2*D floats
    int* deg     = (int*)(scsh + 2 * D);  // N ints (cursor after scan)
    int* ptr     = deg + N;               // N+1 ints
    int* srcbuf  = ptr + N + 1;           // E ints

    const int ELEM4_BLOCKS = (int)(ND / 4 / 256);   // 12500
    const int NODE_BLOCKS  = (N + 3) / 4;           // 12500
    const int GEMM_Y       = (N + BM - 1) / BM;     // 782
    const int STAT_BLOCKS  = (N + 63) / 64;         // 782
    const int E_BLOCKS     = (E + 255) / 256;       // 1172

    // ---- Build CSR (dst-bucketed src list), once per call ----
    hipMemsetAsync(deg, 0, N * sizeof(int), stream);
    hist_dst<<<E_BLOCKS, 256, 0, stream>>>(dst, deg, E);
    scan_deg<<<1, 1024, 0, stream>>>(deg, ptr, N);
    scatter_src<<<E_BLOCKS, 256, 0, stream>>>(src, dst, deg, srcbuf, E);

    for (int l = 0; l < 5; l++) {
        const float* hin = (l == 0) ? x : ((l & 1) ? bufA : bufB);
        float* zb = (l & 1) ? bufB : bufA;
        float* tb = (l & 1) ? bufA : bufB;

        // GINConv aggregation (gather, fused (1+eps)*h): z
        gather_agg<<<NODE_BLOCKS, 256, 0, stream>>>(hin, ptr, srcbuf, zb, eps, l);

        // t = z @ W1 + b1
        gemm_f32<<<dim3(4, GEMM_Y), 256, 0, stream>>>(
            zb, W1 + (size_t)l * D * D, b1 + (size_t)l * D, tb, N);

        // BN1 + relu (in place on t)
        hipMemsetAsync(stats, 0, 2 * D * sizeof(float), stream);
        bn_stats<<<STAT_BLOCKS, 256, 0, stream>>>(tb, stats, N);
        bn_finalize<<<1, 256, 0, stream>>>(stats, g1 + (size_t)l * D,
                                           bt1 + (size_t)l * D, scsh, N);
        bn_apply<<<ELEM4_BLOCKS, 256, 0, stream>>>(tb, tb, scsh, 1);

        // z = t @ W2 + b2
        gemm_f32<<<dim3(4, GEMM_Y), 256, 0, stream>>>(
            tb, W2 + (size_t)l * D * D, b2 + (size_t)l * D, zb, N);

        // BN2 (+ relu except last layer)
        hipMemsetAsync(stats, 0, 2 * D * sizeof(float), stream);
        bn_stats<<<STAT_BLOCKS, 256, 0, stream>>>(zb, stats, N);
        bn_finalize<<<1, 256, 0, stream>>>(stats, bng + (size_t)l * D,
                                           bnb + (size_t)l * D, scsh, N);
        float* outp = (l == 4) ? out : zb;
        bn_apply<<<ELEM4_BLOCKS, 256, 0, stream>>>(zb, outp, scsh, (l < 4) ? 1 : 0);
    }
}

// Round 4
// 986.290 us; speedup vs baseline: 6.7723x; 2.0891x over previous
//
#include <hip/hip_runtime.h>
#include <hip/hip_bf16.h>

#define N_NODES 50000
#define N_EDGES 300000
#define DIM 256
#define MPAD 50048   // 391 * 128

typedef __attribute__((ext_vector_type(8))) _Float16 half8;
typedef __attribute__((ext_vector_type(4))) _Float16 half4;
typedef __attribute__((ext_vector_type(4))) float f32x4;

__device__ __forceinline__ void async16(const void* g, void* l) {
    __builtin_amdgcn_global_load_lds(
        (const __attribute__((address_space(1))) unsigned int*)g,
        (__attribute__((address_space(3))) unsigned int*)l, 16, 0, 0);
}

// ---------------------------------------------------------------------------
// CSR build
// ---------------------------------------------------------------------------
__global__ __launch_bounds__(256) void hist_dst(const int* __restrict__ dst,
                                                int* __restrict__ deg, int E) {
    int e = blockIdx.x * blockDim.x + threadIdx.x;
    if (e < E) atomicAdd(&deg[dst[e]], 1);
}

__global__ __launch_bounds__(1024) void scan_deg(int* __restrict__ deg,
                                                 int* __restrict__ ptr, int n) {
    __shared__ int buf[1024];
    __shared__ int carry_s;
    int tid = threadIdx.x;
    if (tid == 0) carry_s = 0;
    __syncthreads();
    for (int base = 0; base < n; base += 1024) {
        int i = base + tid;
        int v = (i < n) ? deg[i] : 0;
        buf[tid] = v;
        __syncthreads();
        for (int off = 1; off < 1024; off <<= 1) {
            int t = (tid >= off) ? buf[tid - off] : 0;
            __syncthreads();
            buf[tid] += t;
            __syncthreads();
        }
        int incl = buf[tid];
        int excl = incl - v;
        int c = carry_s;
        if (i < n) { ptr[i] = c + excl; deg[i] = c + excl; }
        __syncthreads();
        if (tid == 1023) carry_s += incl;
        __syncthreads();
    }
    if (tid == 0) ptr[n] = carry_s;
}

__global__ __launch_bounds__(256) void scatter_src(const int* __restrict__ src,
                                                   const int* __restrict__ dst,
                                                   int* __restrict__ cursor,
                                                   int* __restrict__ srcbuf, int E) {
    int e = blockIdx.x * blockDim.x + threadIdx.x;
    if (e < E) {
        int pos = atomicAdd(&cursor[dst[e]], 1);
        srcbuf[pos] = src[e];
    }
}

// ---------------------------------------------------------------------------
// x (fp32) -> fp16
// ---------------------------------------------------------------------------
__global__ __launch_bounds__(256) void x2h(const float* __restrict__ x,
                                           _Float16* __restrict__ hb) {
    size_t i = (size_t)blockIdx.x * 256 + threadIdx.x;  // float4 index
    float4 v = ((const float4*)x)[i];
    half4 o;
    o.x = (_Float16)v.x; o.y = (_Float16)v.y;
    o.z = (_Float16)v.z; o.w = (_Float16)v.w;
    ((half4*)hb)[i] = o;
}

// ---------------------------------------------------------------------------
// W (fp32, [K][N] row-major) -> Wt (fp16, [N][K]) for 10 matrices, via LDS tiles
// ---------------------------------------------------------------------------
__global__ __launch_bounds__(256) void wconv(const float* __restrict__ W1,
                                             const float* __restrict__ W2,
                                             _Float16* __restrict__ Wt) {
    int mat = blockIdx.x >> 4;          // 0..4: W1, 5..9: W2
    int t = blockIdx.x & 15;
    int tr = t >> 2, tc = t & 3;        // 64x64 tile at (tr*64, tc*64) of W
    const float* W = (mat < 5) ? (W1 + (size_t)mat * 65536)
                               : (W2 + (size_t)(mat - 5) * 65536);
    __shared__ float tile[64][65];
    int tid = threadIdx.x;
    int c = tid & 63, r0 = tid >> 6;
#pragma unroll 4
    for (int i = 0; i < 16; i++) {
        int r = r0 + i * 4;
        tile[r][c] = W[(size_t)(tr * 64 + r) * 256 + tc * 64 + c];
    }
    __syncthreads();
    _Float16* o = Wt + (size_t)mat * 65536;
#pragma unroll 4
    for (int i = 0; i < 16; i++) {
        int r = r0 + i * 4;   // n_local
        // Wt[n][k] = W[k][n];  n = tc*64 + r, k = tr*64 + c
        o[(size_t)(tc * 64 + r) * 256 + tr * 64 + c] = (_Float16)tile[c][r];
    }
}

// ---------------------------------------------------------------------------
// Gather aggregation (fp16): z[n] = (1+eps)*h[n] + sum relu(h[srcbuf[e]])
// One wave per node, half4 per lane. fp32 accumulation.
// ---------------------------------------------------------------------------
__global__ __launch_bounds__(256) void gather_agg_h(const _Float16* __restrict__ h,
                                                    const int* __restrict__ ptr,
                                                    const int* __restrict__ srcbuf,
                                                    _Float16* __restrict__ z,
                                                    const float* __restrict__ eps,
                                                    int l) {
    int node = blockIdx.x * 4 + (threadIdx.x >> 6);
    if (node >= N_NODES) return;
    int lane = threadIdx.x & 63;
    int beg = ptr[node];
    int end = ptr[node + 1];
    float s = 1.0f + eps[l];
    half4 hv = ((const half4*)(h + (size_t)node * DIM))[lane];
    float a0 = (float)hv.x * s, a1 = (float)hv.y * s;
    float a2 = (float)hv.z * s, a3 = (float)hv.w * s;
    for (int e = beg; e < end; e++) {
        int sn = srcbuf[e];
        half4 v = ((const half4*)(h + (size_t)sn * DIM))[lane];
        a0 += fmaxf((float)v.x, 0.0f);
        a1 += fmaxf((float)v.y, 0.0f);
        a2 += fmaxf((float)v.z, 0.0f);
        a3 += fmaxf((float)v.w, 0.0f);
    }
    half4 o;
    o.x = (_Float16)a0; o.y = (_Float16)a1;
    o.z = (_Float16)a2; o.w = (_Float16)a3;
    ((half4*)(z + (size_t)node * DIM))[lane] = o;
}

// ---------------------------------------------------------------------------
// C[fp16, MPAD x 256] = A[fp16, MPAD x 256] @ Wt^T + bias, fused BN col stats.
// 128x128 tile, 256 thr (4 waves as 2x2 of 64x64), 16x16x32 f16 MFMA, BK=32.
// A staged via global_load_lds width 16 into [m][k] LDS; Wt is [n][k] so B
// stages identically. Fragments: A[m=lane&15][k=quad*8+j]; C: col=lane&15,
// row=quad*4+reg (m89-verified layouts; dtype-independent).
// ---------------------------------------------------------------------------
__global__ __launch_bounds__(256) void gemm_f16(const _Float16* __restrict__ A,
                                                const _Float16* __restrict__ Wt,
                                                const float* __restrict__ bias,
                                                _Float16* __restrict__ C,
                                                float* __restrict__ stats,
                                                int M) {
    __shared__ _Float16 Asm[128 * 32];
    __shared__ _Float16 Bsm[128 * 32];
    __shared__ float colsum[128];
    __shared__ float colsq[128];

    int tid = threadIdx.x;
    int wid = tid >> 6, lane = tid & 63;
    int quad = lane >> 4, lrow = lane & 15;
    int row0 = blockIdx.y * 128, col0 = blockIdx.x * 128;
    int wm = (wid & 1) * 64, wn = (wid >> 1) * 64;

    if (tid < 128) { colsum[tid] = 0.0f; colsq[tid] = 0.0f; }

    f32x4 acc[4][4] = {};

    const char* Ab = (const char*)A;
    const char* Bb = (const char*)Wt;

    for (int k0 = 0; k0 < DIM; k0 += 32) {
#pragma unroll
        for (int j = 0; j < 2; j++) {
            int b = wid * 2048 + j * 1024 + lane * 16;  // byte offset in 8KB tile
            int m = b >> 6;        // row within tile (64B per row)
            int kb = b & 63;       // byte within row
            async16(Ab + (size_t)(row0 + m) * 512 + k0 * 2 + kb,
                    (char*)Asm + wid * 2048 + j * 1024);
            async16(Bb + (size_t)(col0 + m) * 512 + k0 * 2 + kb,
                    (char*)Bsm + wid * 2048 + j * 1024);
        }
        __syncthreads();

        half8 af[4], bf[4];
#pragma unroll
        for (int t = 0; t < 4; t++) {
            af[t] = *(const half8*)(Asm + (wm + t * 16 + lrow) * 32 + quad * 8);
            bf[t] = *(const half8*)(Bsm + (wn + t * 16 + lrow) * 32 + quad * 8);
        }
#pragma unroll
        for (int i = 0; i < 4; i++)
#pragma unroll
            for (int j = 0; j < 4; j++)
                acc[i][j] = __builtin_amdgcn_mfma_f32_16x16x32_f16(
                    af[i], bf[j], acc[i][j], 0, 0, 0);
        __syncthreads();
    }

    // Epilogue: bias add, fp16 store (masked), per-column sum/sumsq partials
    float bcol[4];
#pragma unroll
    for (int j = 0; j < 4; j++) bcol[j] = bias[col0 + wn + j * 16 + lrow];

    float csum[4] = {0.f, 0.f, 0.f, 0.f};
    float csq[4] = {0.f, 0.f, 0.f, 0.f};
#pragma unroll
    for (int i = 0; i < 4; i++) {
        int rbase = row0 + wm + i * 16 + quad * 4;
#pragma unroll
        for (int j = 0; j < 4; j++) {
            int col = col0 + wn + j * 16 + lrow;
#pragma unroll
            for (int r = 0; r < 4; r++) {
                int row = rbase + r;
                if (row < M) {
                    float v = acc[i][j][r] + bcol[j];
                    C[(size_t)row * DIM + col] = (_Float16)v;
                    csum[j] += v;
                    csq[j] += v * v;
                }
            }
        }
    }
#pragma unroll
    for (int j = 0; j < 4; j++) {
        atomicAdd(&colsum[wn + j * 16 + lrow], csum[j]);
        atomicAdd(&colsq[wn + j * 16 + lrow], csq[j]);
    }
    __syncthreads();
    if (tid < 128) {
        atomicAdd(&stats[col0 + tid], colsum[tid]);
        atomicAdd(&stats[DIM + col0 + tid], colsq[tid]);
    }
}

// ---------------------------------------------------------------------------
__global__ __launch_bounds__(256) void bn_finalize(const float* __restrict__ stats,
                                                   const float* __restrict__ g,
                                                   const float* __restrict__ beta,
                                                   float* __restrict__ scsh,
                                                   int n) {
    int d = threadIdx.x;
    float invn = 1.0f / (float)n;
    float mean = stats[d] * invn;
    float var = stats[DIM + d] * invn - mean * mean;
    float inv = rsqrtf(var + 1e-5f);
    float scale = g[d] * inv;
    scsh[d] = scale;
    scsh[DIM + d] = beta[d] - mean * scale;
}

// ---------------------------------------------------------------------------
// BN apply on fp16 C. final_mode=0: relu, write fp16. final_mode=1: no relu,
// write fp32 to outf.
// ---------------------------------------------------------------------------
__global__ __launch_bounds__(256) void bn_apply_h(const _Float16* __restrict__ in,
                                                  _Float16* __restrict__ outb,
                                                  float* __restrict__ outf,
                                                  const float* __restrict__ scsh,
                                                  int final_mode) {
    size_t i = (size_t)blockIdx.x * 256 + threadIdx.x;  // half4 index
    int c4 = (int)(i & 63);
    float4 sc = ((const float4*)scsh)[c4];
    float4 sh = ((const float4*)(scsh + DIM))[c4];
    half4 v = ((const half4*)in)[i];
    float r0 = (float)v.x * sc.x + sh.x;
    float r1 = (float)v.y * sc.y + sh.y;
    float r2 = (float)v.z * sc.z + sh.z;
    float r3 = (float)v.w * sc.w + sh.w;
    if (final_mode) {
        float4 o; o.x = r0; o.y = r1; o.z = r2; o.w = r3;
        ((float4*)outf)[i] = o;
    } else {
        r0 = fmaxf(r0, 0.0f); r1 = fmaxf(r1, 0.0f);
        r2 = fmaxf(r2, 0.0f); r3 = fmaxf(r3, 0.0f);
        half4 o;
        o.x = (_Float16)r0; o.y = (_Float16)r1;
        o.z = (_Float16)r2; o.w = (_Float16)r3;
        ((half4*)outb)[i] = o;
    }
}

// ---------------------------------------------------------------------------
extern "C" void kernel_launch(void* const* d_in, const int* in_sizes, int n_in,
                              void* d_out, int out_size, void* d_ws, size_t ws_size,
                              hipStream_t stream) {
    (void)in_sizes; (void)n_in; (void)out_size; (void)ws_size;
    const float* x   = (const float*)d_in[0];
    const int*   src = (const int*)d_in[1];
    const int*   dst = (const int*)d_in[2];
    const float* W1  = (const float*)d_in[3];
    const float* b1  = (const float*)d_in[4];
    const float* g1  = (const float*)d_in[5];
    const float* bt1 = (const float*)d_in[6];
    const float* W2  = (const float*)d_in[7];
    const float* b2  = (const float*)d_in[8];
    const float* eps = (const float*)d_in[9];
    const float* bng = (const float*)d_in[10];
    const float* bnb = (const float*)d_in[11];
    float* out = (float*)d_out;

    const int N = N_NODES, E = N_EDGES, D = DIM;
    size_t NDp = (size_t)MPAD * D;

    _Float16* hbuf = (_Float16*)d_ws;              // fp16 activations h
    _Float16* gin  = hbuf + NDp;                   // fp16 GEMM input (z / t)
    _Float16* Cb   = gin + NDp;                    // fp16 GEMM output
    _Float16* Wt   = Cb + NDp;                     // 10 * 256*256 fp16 (transposed)
    float* stats = (float*)(Wt + 10 * 65536);      // 1024 f (2 sets of 512)
    float* scsh  = stats + 1024;                   // 512 f
    int* deg     = (int*)(scsh + 512);             // N
    int* ptr     = deg + N;                        // N+1
    int* srcbuf  = ptr + N + 1;                    // E

    const int ELEM4_BLOCKS = N * D / 4 / 256;      // 12500
    const int NODE_BLOCKS  = (N + 3) / 4;          // 12500
    const int E_BLOCKS     = (E + 255) / 256;      // 1172
    const dim3 GEMM_GRID(2, MPAD / 128);           // (2, 391)

    // ---- One-time per call: CSR build, x->fp16, W->fp16 transposed ----
    hipMemsetAsync(deg, 0, N * sizeof(int), stream);
    hist_dst<<<E_BLOCKS, 256, 0, stream>>>(dst, deg, E);
    scan_deg<<<1, 1024, 0, stream>>>(deg, ptr, N);
    scatter_src<<<E_BLOCKS, 256, 0, stream>>>(src, dst, deg, srcbuf, E);
    x2h<<<ELEM4_BLOCKS, 256, 0, stream>>>(x, hbuf);
    wconv<<<160, 256, 0, stream>>>(W1, W2, Wt);

    for (int l = 0; l < 5; l++) {
        // z = (1+eps)*h + gather-sum(relu(h[src]))  -> gin (fp16)
        gather_agg_h<<<NODE_BLOCKS, 256, 0, stream>>>(hbuf, ptr, srcbuf, gin, eps, l);

        hipMemsetAsync(stats, 0, 1024 * sizeof(float), stream);

        // C = gin @ W1 + b1, fused BN1 stats
        gemm_f16<<<GEMM_GRID, 256, 0, stream>>>(
            gin, Wt + (size_t)l * 65536, b1 + (size_t)l * D, Cb, stats, N);
        bn_finalize<<<1, 256, 0, stream>>>(stats, g1 + (size_t)l * D,
                                           bt1 + (size_t)l * D, scsh, N);
        bn_apply_h<<<ELEM4_BLOCKS, 256, 0, stream>>>(Cb, gin, nullptr, scsh, 0);

        // C = gin @ W2 + b2, fused BN2 stats
        gemm_f16<<<GEMM_GRID, 256, 0, stream>>>(
            gin, Wt + (size_t)(5 + l) * 65536, b2 + (size_t)l * D, Cb, stats + 512, N);
        bn_finalize<<<1, 256, 0, stream>>>(stats + 512, bng + (size_t)l * D,
                                           bnb + (size_t)l * D, scsh, N);
        // h_next (fp16) or final fp32 output
        bn_apply_h<<<ELEM4_BLOCKS, 256, 0, stream>>>(
            Cb, hbuf, out, scsh, (l == 4) ? 1 : 0);
    }
}

// Round 5
// 805.371 us; speedup vs baseline: 8.2936x; 1.2246x over previous
//
#include <hip/hip_runtime.h>
#include <hip/hip_bf16.h>

#define N_NODES 50000
#define N_EDGES 300000
#define DIM 256
#define MPAD 50048   // 391 * 128

typedef __attribute__((ext_vector_type(8))) _Float16 half8;
typedef __attribute__((ext_vector_type(4))) _Float16 half4;
typedef __attribute__((ext_vector_type(4))) float f32x4;

__device__ __forceinline__ void async16(const void* g, void* l) {
    __builtin_amdgcn_global_load_lds(
        (const __attribute__((address_space(1))) unsigned int*)g,
        (__attribute__((address_space(3))) unsigned int*)l, 16, 0, 0);
}

// ---------------------------------------------------------------------------
// CSR build: histogram
// ---------------------------------------------------------------------------
__global__ __launch_bounds__(256) void hist_dst(const int* __restrict__ dst,
                                                int* __restrict__ deg, int E) {
    int e = blockIdx.x * blockDim.x + threadIdx.x;
    if (e < E) atomicAdd(&deg[dst[e]], 1);
}

// ---------------------------------------------------------------------------
// Hierarchical scan, step 1: per-block (1024-elem chunk) exclusive scan.
// Wave shuffle scan + LDS combine. Writes local-exclusive to ptr, block total
// to bsum.
// ---------------------------------------------------------------------------
__global__ __launch_bounds__(1024) void scan_blk(const int* __restrict__ deg,
                                                 int* __restrict__ ptr,
                                                 int* __restrict__ bsum, int n) {
    __shared__ int wsum[16];
    __shared__ int wpre[16];
    int tid = threadIdx.x;
    int i = blockIdx.x * 1024 + tid;
    int v = (i < n) ? deg[i] : 0;
    int lane = tid & 63, w = tid >> 6;
    int s = v;
#pragma unroll
    for (int off = 1; off < 64; off <<= 1) {
        int t = __shfl_up(s, off, 64);
        if (lane >= off) s += t;
    }
    if (lane == 63) wsum[w] = s;
    __syncthreads();
    if (tid < 16) {
        int acc = 0;
        for (int j = 0; j < tid; j++) acc += wsum[j];
        wpre[tid] = acc;
    }
    __syncthreads();
    int incl = s + wpre[w];
    if (i < n) ptr[i] = incl - v;            // local exclusive
    if (tid == 1023) bsum[blockIdx.x] = incl; // block total
}

// ---------------------------------------------------------------------------
// Scan step 2: single wave scans block totals (nb <= 64) to exclusive.
// ---------------------------------------------------------------------------
__global__ __launch_bounds__(64) void scan_top(int* __restrict__ bsum,
                                               int* __restrict__ ptr,
                                               int nb, int n, int E) {
    int lane = threadIdx.x;
    int v = (lane < nb) ? bsum[lane] : 0;
    int s = v;
#pragma unroll
    for (int off = 1; off < 64; off <<= 1) {
        int t = __shfl_up(s, off, 64);
        if (lane >= off) s += t;
    }
    if (lane < nb) bsum[lane] = s - v;  // exclusive
    if (lane == 0) ptr[n] = E;
}

// ---------------------------------------------------------------------------
// Scan step 3: add block offset; duplicate into cursor (deg reused).
// ---------------------------------------------------------------------------
__global__ __launch_bounds__(1024) void scan_add(int* __restrict__ ptr,
                                                 const int* __restrict__ bsum,
                                                 int* __restrict__ cursor, int n) {
    int i = blockIdx.x * 1024 + threadIdx.x;
    if (i < n) {
        int val = ptr[i] + bsum[blockIdx.x];
        ptr[i] = val;
        cursor[i] = val;
    }
}

// ---------------------------------------------------------------------------
// CSR build: counting-sort scatter
// ---------------------------------------------------------------------------
__global__ __launch_bounds__(256) void scatter_src(const int* __restrict__ src,
                                                   const int* __restrict__ dst,
                                                   int* __restrict__ cursor,
                                                   int* __restrict__ srcbuf, int E) {
    int e = blockIdx.x * blockDim.x + threadIdx.x;
    if (e < E) {
        int pos = atomicAdd(&cursor[dst[e]], 1);
        srcbuf[pos] = src[e];
    }
}

// ---------------------------------------------------------------------------
// W (fp32, [K][N] row-major) -> Wt (fp16, [N][K]) for 10 matrices
// ---------------------------------------------------------------------------
__global__ __launch_bounds__(256) void wconv(const float* __restrict__ W1,
                                             const float* __restrict__ W2,
                                             _Float16* __restrict__ Wt) {
    int mat = blockIdx.x >> 4;
    int t = blockIdx.x & 15;
    int tr = t >> 2, tc = t & 3;
    const float* W = (mat < 5) ? (W1 + (size_t)mat * 65536)
                               : (W2 + (size_t)(mat - 5) * 65536);
    __shared__ float tile[64][65];
    int tid = threadIdx.x;
    int c = tid & 63, r0 = tid >> 6;
#pragma unroll 4
    for (int i = 0; i < 16; i++) {
        int r = r0 + i * 4;
        tile[r][c] = W[(size_t)(tr * 64 + r) * 256 + tc * 64 + c];
    }
    __syncthreads();
    _Float16* o = Wt + (size_t)mat * 65536;
#pragma unroll 4
    for (int i = 0; i < 16; i++) {
        int r = r0 + i * 4;
        o[(size_t)(tc * 64 + r) * 256 + tr * 64 + c] = (_Float16)tile[c][r];
    }
}

// ---------------------------------------------------------------------------
// Layer-0 gather: z[n] = (1+eps)*x[n] + sum relu(x[src]); x is fp32.
// One wave per node, float4 per lane, edge loop unrolled x4 for MLP.
// ---------------------------------------------------------------------------
__global__ __launch_bounds__(256) void gather_x(const float* __restrict__ x,
                                                const int* __restrict__ ptr,
                                                const int* __restrict__ srcbuf,
                                                _Float16* __restrict__ z,
                                                const float* __restrict__ eps) {
    int node = blockIdx.x * 4 + (threadIdx.x >> 6);
    if (node >= N_NODES) return;
    int lane = threadIdx.x & 63;
    int beg = ptr[node], end = ptr[node + 1];
    float s = 1.0f + eps[0];
    float4 hv = ((const float4*)(x + (size_t)node * DIM))[lane];
    float a0 = hv.x * s, a1 = hv.y * s, a2 = hv.z * s, a3 = hv.w * s;
    int e = beg;
    for (; e + 4 <= end; e += 4) {
        int s0 = srcbuf[e], s1 = srcbuf[e + 1], s2 = srcbuf[e + 2], s3 = srcbuf[e + 3];
        float4 v0 = ((const float4*)(x + (size_t)s0 * DIM))[lane];
        float4 v1 = ((const float4*)(x + (size_t)s1 * DIM))[lane];
        float4 v2 = ((const float4*)(x + (size_t)s2 * DIM))[lane];
        float4 v3 = ((const float4*)(x + (size_t)s3 * DIM))[lane];
        a0 += fmaxf(v0.x, 0.f) + fmaxf(v1.x, 0.f) + fmaxf(v2.x, 0.f) + fmaxf(v3.x, 0.f);
        a1 += fmaxf(v0.y, 0.f) + fmaxf(v1.y, 0.f) + fmaxf(v2.y, 0.f) + fmaxf(v3.y, 0.f);
        a2 += fmaxf(v0.z, 0.f) + fmaxf(v1.z, 0.f) + fmaxf(v2.z, 0.f) + fmaxf(v3.z, 0.f);
        a3 += fmaxf(v0.w, 0.f) + fmaxf(v1.w, 0.f) + fmaxf(v2.w, 0.f) + fmaxf(v3.w, 0.f);
    }
    for (; e < end; e++) {
        float4 v = ((const float4*)(x + (size_t)srcbuf[e] * DIM))[lane];
        a0 += fmaxf(v.x, 0.f); a1 += fmaxf(v.y, 0.f);
        a2 += fmaxf(v.z, 0.f); a3 += fmaxf(v.w, 0.f);
    }
    half4 o;
    o.x = (_Float16)a0; o.y = (_Float16)a1;
    o.z = (_Float16)a2; o.w = (_Float16)a3;
    ((half4*)(z + (size_t)node * DIM))[lane] = o;
}

// ---------------------------------------------------------------------------
// Layers 1..4 gather with fused BN2: h = relu(scale*C + shift) computed
// on the fly; z[n] = (1+eps)*h[n] + sum h[src]. C is raw GEMM2 output (fp16).
// ---------------------------------------------------------------------------
__global__ __launch_bounds__(256) void gather_bn(const _Float16* __restrict__ C,
                                                 const int* __restrict__ ptr,
                                                 const int* __restrict__ srcbuf,
                                                 _Float16* __restrict__ z,
                                                 const float* __restrict__ scsh,
                                                 const float* __restrict__ eps,
                                                 int l) {
    int node = blockIdx.x * 4 + (threadIdx.x >> 6);
    if (node >= N_NODES) return;
    int lane = threadIdx.x & 63;
    float4 sc = ((const float4*)scsh)[lane];
    float4 sh = ((const float4*)(scsh + DIM))[lane];
    int beg = ptr[node], end = ptr[node + 1];
    float s = 1.0f + eps[l];
    half4 hv = ((const half4*)(C + (size_t)node * DIM))[lane];
    float a0 = s * fmaxf((float)hv.x * sc.x + sh.x, 0.f);
    float a1 = s * fmaxf((float)hv.y * sc.y + sh.y, 0.f);
    float a2 = s * fmaxf((float)hv.z * sc.z + sh.z, 0.f);
    float a3 = s * fmaxf((float)hv.w * sc.w + sh.w, 0.f);
    int e = beg;
    for (; e + 4 <= end; e += 4) {
        int s0 = srcbuf[e], s1 = srcbuf[e + 1], s2 = srcbuf[e + 2], s3 = srcbuf[e + 3];
        half4 v0 = ((const half4*)(C + (size_t)s0 * DIM))[lane];
        half4 v1 = ((const half4*)(C + (size_t)s1 * DIM))[lane];
        half4 v2 = ((const half4*)(C + (size_t)s2 * DIM))[lane];
        half4 v3 = ((const half4*)(C + (size_t)s3 * DIM))[lane];
        a0 += fmaxf((float)v0.x * sc.x + sh.x, 0.f) + fmaxf((float)v1.x * sc.x + sh.x, 0.f)
            + fmaxf((float)v2.x * sc.x + sh.x, 0.f) + fmaxf((float)v3.x * sc.x + sh.x, 0.f);
        a1 += fmaxf((float)v0.y * sc.y + sh.y, 0.f) + fmaxf((float)v1.y * sc.y + sh.y, 0.f)
            + fmaxf((float)v2.y * sc.y + sh.y, 0.f) + fmaxf((float)v3.y * sc.y + sh.y, 0.f);
        a2 += fmaxf((float)v0.z * sc.z + sh.z, 0.f) + fmaxf((float)v1.z * sc.z + sh.z, 0.f)
            + fmaxf((float)v2.z * sc.z + sh.z, 0.f) + fmaxf((float)v3.z * sc.z + sh.z, 0.f);
        a3 += fmaxf((float)v0.w * sc.w + sh.w, 0.f) + fmaxf((float)v1.w * sc.w + sh.w, 0.f)
            + fmaxf((float)v2.w * sc.w + sh.w, 0.f) + fmaxf((float)v3.w * sc.w + sh.w, 0.f);
    }
    for (; e < end; e++) {
        half4 v = ((const half4*)(C + (size_t)srcbuf[e] * DIM))[lane];
        a0 += fmaxf((float)v.x * sc.x + sh.x, 0.f);
        a1 += fmaxf((float)v.y * sc.y + sh.y, 0.f);
        a2 += fmaxf((float)v.z * sc.z + sh.z, 0.f);
        a3 += fmaxf((float)v.w * sc.w + sh.w, 0.f);
    }
    half4 o;
    o.x = (_Float16)a0; o.y = (_Float16)a1;
    o.z = (_Float16)a2; o.w = (_Float16)a3;
    ((half4*)(z + (size_t)node * DIM))[lane] = o;
}

// ---------------------------------------------------------------------------
// C[fp16, MPAD x 256] = A[fp16] @ Wt^T + bias, fused BN col stats.
// ---------------------------------------------------------------------------
__global__ __launch_bounds__(256) void gemm_f16(const _Float16* __restrict__ A,
                                                const _Float16* __restrict__ Wt,
                                                const float* __restrict__ bias,
                                                _Float16* __restrict__ C,
                                                float* __restrict__ stats,
                                                int M) {
    __shared__ _Float16 Asm[128 * 32];
    __shared__ _Float16 Bsm[128 * 32];
    __shared__ float colsum[128];
    __shared__ float colsq[128];

    int tid = threadIdx.x;
    int wid = tid >> 6, lane = tid & 63;
    int quad = lane >> 4, lrow = lane & 15;
    int row0 = blockIdx.y * 128, col0 = blockIdx.x * 128;
    int wm = (wid & 1) * 64, wn = (wid >> 1) * 64;

    if (tid < 128) { colsum[tid] = 0.0f; colsq[tid] = 0.0f; }

    f32x4 acc[4][4] = {};

    const char* Ab = (const char*)A;
    const char* Bb = (const char*)Wt;

    for (int k0 = 0; k0 < DIM; k0 += 32) {
#pragma unroll
        for (int j = 0; j < 2; j++) {
            int b = wid * 2048 + j * 1024 + lane * 16;
            int m = b >> 6;
            int kb = b & 63;
            async16(Ab + (size_t)(row0 + m) * 512 + k0 * 2 + kb,
                    (char*)Asm + wid * 2048 + j * 1024);
            async16(Bb + (size_t)(col0 + m) * 512 + k0 * 2 + kb,
                    (char*)Bsm + wid * 2048 + j * 1024);
        }
        __syncthreads();

        half8 af[4], bf[4];
#pragma unroll
        for (int t = 0; t < 4; t++) {
            af[t] = *(const half8*)(Asm + (wm + t * 16 + lrow) * 32 + quad * 8);
            bf[t] = *(const half8*)(Bsm + (wn + t * 16 + lrow) * 32 + quad * 8);
        }
#pragma unroll
        for (int i = 0; i < 4; i++)
#pragma unroll
            for (int j = 0; j < 4; j++)
                acc[i][j] = __builtin_amdgcn_mfma_f32_16x16x32_f16(
                    af[i], bf[j], acc[i][j], 0, 0, 0);
        __syncthreads();
    }

    float bcol[4];
#pragma unroll
    for (int j = 0; j < 4; j++) bcol[j] = bias[col0 + wn + j * 16 + lrow];

    float csum[4] = {0.f, 0.f, 0.f, 0.f};
    float csq[4] = {0.f, 0.f, 0.f, 0.f};
#pragma unroll
    for (int i = 0; i < 4; i++) {
        int rbase = row0 + wm + i * 16 + quad * 4;
#pragma unroll
        for (int j = 0; j < 4; j++) {
            int col = col0 + wn + j * 16 + lrow;
#pragma unroll
            for (int r = 0; r < 4; r++) {
                int row = rbase + r;
                if (row < M) {
                    float v = acc[i][j][r] + bcol[j];
                    C[(size_t)row * DIM + col] = (_Float16)v;
                    csum[j] += v;
                    csq[j] += v * v;
                }
            }
        }
    }
#pragma unroll
    for (int j = 0; j < 4; j++) {
        atomicAdd(&colsum[wn + j * 16 + lrow], csum[j]);
        atomicAdd(&colsq[wn + j * 16 + lrow], csq[j]);
    }
    __syncthreads();
    if (tid < 128) {
        atomicAdd(&stats[col0 + tid], colsum[tid]);
        atomicAdd(&stats[DIM + col0 + tid], colsq[tid]);
    }
}

// ---------------------------------------------------------------------------
// Finalize BN; zeroes its stats buffer for the next layer's accumulation.
// ---------------------------------------------------------------------------
__global__ __launch_bounds__(256) void bn_finalize(float* __restrict__ stats,
                                                   const float* __restrict__ g,
                                                   const float* __restrict__ beta,
                                                   float* __restrict__ scsh,
                                                   int n) {
    int d = threadIdx.x;
    float invn = 1.0f / (float)n;
    float mean = stats[d] * invn;
    float var = stats[DIM + d] * invn - mean * mean;
    float inv = rsqrtf(var + 1e-5f);
    float scale = g[d] * inv;
    scsh[d] = scale;
    scsh[DIM + d] = beta[d] - mean * scale;
    stats[d] = 0.0f;
    stats[DIM + d] = 0.0f;
}

// ---------------------------------------------------------------------------
// BN apply: mid-MLP (relu, fp16 out) or final (no relu, fp32 out).
// ---------------------------------------------------------------------------
__global__ __launch_bounds__(256) void bn_apply_h(const _Float16* __restrict__ in,
                                                  _Float16* __restrict__ outb,
                                                  float* __restrict__ outf,
                                                  const float* __restrict__ scsh,
                                                  int final_mode) {
    size_t i = (size_t)blockIdx.x * 256 + threadIdx.x;
    int c4 = (int)(i & 63);
    float4 sc = ((const float4*)scsh)[c4];
    float4 sh = ((const float4*)(scsh + DIM))[c4];
    half4 v = ((const half4*)in)[i];
    float r0 = (float)v.x * sc.x + sh.x;
    float r1 = (float)v.y * sc.y + sh.y;
    float r2 = (float)v.z * sc.z + sh.z;
    float r3 = (float)v.w * sc.w + sh.w;
    if (final_mode) {
        float4 o; o.x = r0; o.y = r1; o.z = r2; o.w = r3;
        ((float4*)outf)[i] = o;
    } else {
        r0 = fmaxf(r0, 0.0f); r1 = fmaxf(r1, 0.0f);
        r2 = fmaxf(r2, 0.0f); r3 = fmaxf(r3, 0.0f);
        half4 o;
        o.x = (_Float16)r0; o.y = (_Float16)r1;
        o.z = (_Float16)r2; o.w = (_Float16)r3;
        ((half4*)outb)[i] = o;
    }
}

// ---------------------------------------------------------------------------
extern "C" void kernel_launch(void* const* d_in, const int* in_sizes, int n_in,
                              void* d_out, int out_size, void* d_ws, size_t ws_size,
                              hipStream_t stream) {
    (void)in_sizes; (void)n_in; (void)out_size; (void)ws_size;
    const float* x   = (const float*)d_in[0];
    const int*   src = (const int*)d_in[1];
    const int*   dst = (const int*)d_in[2];
    const float* W1  = (const float*)d_in[3];
    const float* b1  = (const float*)d_in[4];
    const float* g1  = (const float*)d_in[5];
    const float* bt1 = (const float*)d_in[6];
    const float* W2  = (const float*)d_in[7];
    const float* b2  = (const float*)d_in[8];
    const float* eps = (const float*)d_in[9];
    const float* bng = (const float*)d_in[10];
    const float* bnb = (const float*)d_in[11];
    float* out = (float*)d_out;

    const int N = N_NODES, E = N_EDGES, D = DIM;
    size_t NDp = (size_t)MPAD * D;

    _Float16* gin  = (_Float16*)d_ws;              // fp16 GEMM input (z / t)
    _Float16* Cb   = gin + NDp;                    // fp16 GEMM output
    _Float16* Wt   = Cb + NDp;                     // 10 * 256*256 fp16
    float* stats = (float*)(Wt + 10 * 65536);      // 1024 f (2 sets of 512)
    float* scshA = stats + 1024;                   // 512 f (BN1)
    float* scshB = scshA + 512;                    // 512 f (BN2)
    int* deg     = (int*)(scshB + 512);            // N (cursor)
    int* ptr     = deg + N;                        // N+1
    int* bsum    = ptr + N + 1;                    // 64
    int* srcbuf  = bsum + 64;                      // E

    const int ELEM4_BLOCKS = N * D / 4 / 256;      // 12500
    const int NODE_BLOCKS  = (N + 3) / 4;          // 12500
    const int E_BLOCKS     = (E + 255) / 256;      // 1172
    const int SCAN_BLOCKS  = (N + 1023) / 1024;    // 49
    const dim3 GEMM_GRID(2, MPAD / 128);           // (2, 391)

    // ---- One-time per call: CSR build, stats zero, W->fp16 transposed ----
    hipMemsetAsync(deg, 0, N * sizeof(int), stream);
    hipMemsetAsync(stats, 0, 1024 * sizeof(float), stream);
    hist_dst<<<E_BLOCKS, 256, 0, stream>>>(dst, deg, E);
    scan_blk<<<SCAN_BLOCKS, 1024, 0, stream>>>(deg, ptr, bsum, N);
    scan_top<<<1, 64, 0, stream>>>(bsum, ptr, SCAN_BLOCKS, N, E);
    scan_add<<<SCAN_BLOCKS, 1024, 0, stream>>>(ptr, bsum, deg, N);
    scatter_src<<<E_BLOCKS, 256, 0, stream>>>(src, dst, deg, srcbuf, E);
    wconv<<<160, 256, 0, stream>>>(W1, W2, Wt);

    for (int l = 0; l < 5; l++) {
        // Gather (+ fused BN2-of-previous-layer for l>=1) -> gin (fp16)
        if (l == 0)
            gather_x<<<NODE_BLOCKS, 256, 0, stream>>>(x, ptr, srcbuf, gin, eps);
        else
            gather_bn<<<NODE_BLOCKS, 256, 0, stream>>>(Cb, ptr, srcbuf, gin,
                                                       scshB, eps, l);

        // C = gin @ W1 + b1, fused BN1 stats
        gemm_f16<<<GEMM_GRID, 256, 0, stream>>>(
            gin, Wt + (size_t)l * 65536, b1 + (size_t)l * D, Cb, stats, N);
        bn_finalize<<<1, 256, 0, stream>>>(stats, g1 + (size_t)l * D,
                                           bt1 + (size_t)l * D, scshA, N);
        // mid-MLP BN1 + relu: Cb -> gin
        bn_apply_h<<<ELEM4_BLOCKS, 256, 0, stream>>>(Cb, gin, nullptr, scshA, 0);

        // C = gin @ W2 + b2, fused BN2 stats
        gemm_f16<<<GEMM_GRID, 256, 0, stream>>>(
            gin, Wt + (size_t)(5 + l) * 65536, b2 + (size_t)l * D, Cb, stats + 512, N);
        bn_finalize<<<1, 256, 0, stream>>>(stats + 512, bng + (size_t)l * D,
                                           bnb + (size_t)l * D, scshB, N);
        // BN2 is consumed fused in next layer's gather; final layer writes out.
        if (l == 4)
            bn_apply_h<<<ELEM4_BLOCKS, 256, 0, stream>>>(Cb, nullptr, out, scshB, 1);
    }
}

// Round 6
// 746.220 us; speedup vs baseline: 8.9511x; 1.0793x over previous
//
#include <hip/hip_runtime.h>
#include <hip/hip_bf16.h>

#define N_NODES 50000
#define N_EDGES 300000
#define DIM 256
#define MPAD 50048   // 391 * 128

typedef __attribute__((ext_vector_type(8))) _Float16 half8;
typedef __attribute__((ext_vector_type(4))) _Float16 half4;
typedef __attribute__((ext_vector_type(4))) float f32x4;

__device__ __forceinline__ void async16(const void* g, void* l) {
    __builtin_amdgcn_global_load_lds(
        (const __attribute__((address_space(1))) unsigned int*)g,
        (__attribute__((address_space(3))) unsigned int*)l, 16, 0, 0);
}

// ---------------------------------------------------------------------------
// CSR build: histogram
// ---------------------------------------------------------------------------
__global__ __launch_bounds__(256) void hist_dst(const int* __restrict__ dst,
                                                int* __restrict__ deg, int E) {
    int e = blockIdx.x * blockDim.x + threadIdx.x;
    if (e < E) atomicAdd(&deg[dst[e]], 1);
}

// ---------------------------------------------------------------------------
// Hierarchical scan, step 1: per-block (1024) exclusive scan via wave shuffles.
// ---------------------------------------------------------------------------
__global__ __launch_bounds__(1024) void scan_blk(const int* __restrict__ deg,
                                                 int* __restrict__ ptr,
                                                 int* __restrict__ bsum, int n) {
    __shared__ int wsum[16];
    __shared__ int wpre[16];
    int tid = threadIdx.x;
    int i = blockIdx.x * 1024 + tid;
    int v = (i < n) ? deg[i] : 0;
    int lane = tid & 63, w = tid >> 6;
    int s = v;
#pragma unroll
    for (int off = 1; off < 64; off <<= 1) {
        int t = __shfl_up(s, off, 64);
        if (lane >= off) s += t;
    }
    if (lane == 63) wsum[w] = s;
    __syncthreads();
    if (tid < 16) {
        int acc = 0;
        for (int j = 0; j < tid; j++) acc += wsum[j];
        wpre[tid] = acc;
    }
    __syncthreads();
    int incl = s + wpre[w];
    if (i < n) ptr[i] = incl - v;
    if (tid == 1023) bsum[blockIdx.x] = incl;
}

// ---------------------------------------------------------------------------
// Scan step 2: single wave scans block totals (nb <= 64).
// ---------------------------------------------------------------------------
__global__ __launch_bounds__(64) void scan_top(int* __restrict__ bsum,
                                               int* __restrict__ ptr,
                                               int nb, int n, int E) {
    int lane = threadIdx.x;
    int v = (lane < nb) ? bsum[lane] : 0;
    int s = v;
#pragma unroll
    for (int off = 1; off < 64; off <<= 1) {
        int t = __shfl_up(s, off, 64);
        if (lane >= off) s += t;
    }
    if (lane < nb) bsum[lane] = s - v;
    if (lane == 0) ptr[n] = E;
}

// ---------------------------------------------------------------------------
// Scan step 3: add block offset; duplicate into cursor.
// ---------------------------------------------------------------------------
__global__ __launch_bounds__(1024) void scan_add(int* __restrict__ ptr,
                                                 const int* __restrict__ bsum,
                                                 int* __restrict__ cursor, int n) {
    int i = blockIdx.x * 1024 + threadIdx.x;
    if (i < n) {
        int val = ptr[i] + bsum[blockIdx.x];
        ptr[i] = val;
        cursor[i] = val;
    }
}

// ---------------------------------------------------------------------------
// CSR build: counting-sort scatter
// ---------------------------------------------------------------------------
__global__ __launch_bounds__(256) void scatter_src(const int* __restrict__ src,
                                                   const int* __restrict__ dst,
                                                   int* __restrict__ cursor,
                                                   int* __restrict__ srcbuf, int E) {
    int e = blockIdx.x * blockDim.x + threadIdx.x;
    if (e < E) {
        int pos = atomicAdd(&cursor[dst[e]], 1);
        srcbuf[pos] = src[e];
    }
}

// ---------------------------------------------------------------------------
// x (fp32) -> fp16
// ---------------------------------------------------------------------------
__global__ __launch_bounds__(256) void x2h(const float* __restrict__ x,
                                           _Float16* __restrict__ hb) {
    size_t i = (size_t)blockIdx.x * 256 + threadIdx.x;  // float4 index
    float4 v = ((const float4*)x)[i];
    half4 o;
    o.x = (_Float16)v.x; o.y = (_Float16)v.y;
    o.z = (_Float16)v.z; o.w = (_Float16)v.w;
    ((half4*)hb)[i] = o;
}

// ---------------------------------------------------------------------------
// W (fp32, [K][N] row-major) -> Wt (fp16, [N][K]) for 10 matrices
// ---------------------------------------------------------------------------
__global__ __launch_bounds__(256) void wconv(const float* __restrict__ W1,
                                             const float* __restrict__ W2,
                                             _Float16* __restrict__ Wt) {
    int mat = blockIdx.x >> 4;
    int t = blockIdx.x & 15;
    int tr = t >> 2, tc = t & 3;
    const float* W = (mat < 5) ? (W1 + (size_t)mat * 65536)
                               : (W2 + (size_t)(mat - 5) * 65536);
    __shared__ float tile[64][65];
    int tid = threadIdx.x;
    int c = tid & 63, r0 = tid >> 6;
#pragma unroll 4
    for (int i = 0; i < 16; i++) {
        int r = r0 + i * 4;
        tile[r][c] = W[(size_t)(tr * 64 + r) * 256 + tc * 64 + c];
    }
    __syncthreads();
    _Float16* o = Wt + (size_t)mat * 65536;
#pragma unroll 4
    for (int i = 0; i < 16; i++) {
        int r = r0 + i * 4;
        o[(size_t)(tc * 64 + r) * 256 + tr * 64 + c] = (_Float16)tile[c][r];
    }
}

// ---------------------------------------------------------------------------
// Layer-0 gather (fp16 x): z[n] = (1+eps)*xh[n] + sum relu(xh[src]).
// ---------------------------------------------------------------------------
__global__ __launch_bounds__(256) void gather_h(const _Float16* __restrict__ h,
                                                const int* __restrict__ ptr,
                                                const int* __restrict__ srcbuf,
                                                _Float16* __restrict__ z,
                                                const float* __restrict__ eps) {
    int node = blockIdx.x * 4 + (threadIdx.x >> 6);
    if (node >= N_NODES) return;
    int lane = threadIdx.x & 63;
    int beg = ptr[node], end = ptr[node + 1];
    float s = 1.0f + eps[0];
    half4 hv = ((const half4*)(h + (size_t)node * DIM))[lane];
    float a0 = (float)hv.x * s, a1 = (float)hv.y * s;
    float a2 = (float)hv.z * s, a3 = (float)hv.w * s;
    int e = beg;
    for (; e + 4 <= end; e += 4) {
        int s0 = srcbuf[e], s1 = srcbuf[e + 1], s2 = srcbuf[e + 2], s3 = srcbuf[e + 3];
        half4 v0 = ((const half4*)(h + (size_t)s0 * DIM))[lane];
        half4 v1 = ((const half4*)(h + (size_t)s1 * DIM))[lane];
        half4 v2 = ((const half4*)(h + (size_t)s2 * DIM))[lane];
        half4 v3 = ((const half4*)(h + (size_t)s3 * DIM))[lane];
        a0 += fmaxf((float)v0.x, 0.f) + fmaxf((float)v1.x, 0.f)
            + fmaxf((float)v2.x, 0.f) + fmaxf((float)v3.x, 0.f);
        a1 += fmaxf((float)v0.y, 0.f) + fmaxf((float)v1.y, 0.f)
            + fmaxf((float)v2.y, 0.f) + fmaxf((float)v3.y, 0.f);
        a2 += fmaxf((float)v0.z, 0.f) + fmaxf((float)v1.z, 0.f)
            + fmaxf((float)v2.z, 0.f) + fmaxf((float)v3.z, 0.f);
        a3 += fmaxf((float)v0.w, 0.f) + fmaxf((float)v1.w, 0.f)
            + fmaxf((float)v2.w, 0.f) + fmaxf((float)v3.w, 0.f);
    }
    for (; e < end; e++) {
        half4 v = ((const half4*)(h + (size_t)srcbuf[e] * DIM))[lane];
        a0 += fmaxf((float)v.x, 0.f); a1 += fmaxf((float)v.y, 0.f);
        a2 += fmaxf((float)v.z, 0.f); a3 += fmaxf((float)v.w, 0.f);
    }
    half4 o;
    o.x = (_Float16)a0; o.y = (_Float16)a1;
    o.z = (_Float16)a2; o.w = (_Float16)a3;
    ((half4*)(z + (size_t)node * DIM))[lane] = o;
}

// ---------------------------------------------------------------------------
// Layers 1..4 gather with fused BN2: h = relu(scale*C + shift) on the fly.
// ---------------------------------------------------------------------------
__global__ __launch_bounds__(256) void gather_bn(const _Float16* __restrict__ C,
                                                 const int* __restrict__ ptr,
                                                 const int* __restrict__ srcbuf,
                                                 _Float16* __restrict__ z,
                                                 const float* __restrict__ scsh,
                                                 const float* __restrict__ eps,
                                                 int l) {
    int node = blockIdx.x * 4 + (threadIdx.x >> 6);
    if (node >= N_NODES) return;
    int lane = threadIdx.x & 63;
    float4 sc = ((const float4*)scsh)[lane];
    float4 sh = ((const float4*)(scsh + DIM))[lane];
    int beg = ptr[node], end = ptr[node + 1];
    float s = 1.0f + eps[l];
    half4 hv = ((const half4*)(C + (size_t)node * DIM))[lane];
    float a0 = s * fmaxf((float)hv.x * sc.x + sh.x, 0.f);
    float a1 = s * fmaxf((float)hv.y * sc.y + sh.y, 0.f);
    float a2 = s * fmaxf((float)hv.z * sc.z + sh.z, 0.f);
    float a3 = s * fmaxf((float)hv.w * sc.w + sh.w, 0.f);
    int e = beg;
    for (; e + 4 <= end; e += 4) {
        int s0 = srcbuf[e], s1 = srcbuf[e + 1], s2 = srcbuf[e + 2], s3 = srcbuf[e + 3];
        half4 v0 = ((const half4*)(C + (size_t)s0 * DIM))[lane];
        half4 v1 = ((const half4*)(C + (size_t)s1 * DIM))[lane];
        half4 v2 = ((const half4*)(C + (size_t)s2 * DIM))[lane];
        half4 v3 = ((const half4*)(C + (size_t)s3 * DIM))[lane];
        a0 += fmaxf((float)v0.x * sc.x + sh.x, 0.f) + fmaxf((float)v1.x * sc.x + sh.x, 0.f)
            + fmaxf((float)v2.x * sc.x + sh.x, 0.f) + fmaxf((float)v3.x * sc.x + sh.x, 0.f);
        a1 += fmaxf((float)v0.y * sc.y + sh.y, 0.f) + fmaxf((float)v1.y * sc.y + sh.y, 0.f)
            + fmaxf((float)v2.y * sc.y + sh.y, 0.f) + fmaxf((float)v3.y * sc.y + sh.y, 0.f);
        a2 += fmaxf((float)v0.z * sc.z + sh.z, 0.f) + fmaxf((float)v1.z * sc.z + sh.z, 0.f)
            + fmaxf((float)v2.z * sc.z + sh.z, 0.f) + fmaxf((float)v3.z * sc.z + sh.z, 0.f);
        a3 += fmaxf((float)v0.w * sc.w + sh.w, 0.f) + fmaxf((float)v1.w * sc.w + sh.w, 0.f)
            + fmaxf((float)v2.w * sc.w + sh.w, 0.f) + fmaxf((float)v3.w * sc.w + sh.w, 0.f);
    }
    for (; e < end; e++) {
        half4 v = ((const half4*)(C + (size_t)srcbuf[e] * DIM))[lane];
        a0 += fmaxf((float)v.x * sc.x + sh.x, 0.f);
        a1 += fmaxf((float)v.y * sc.y + sh.y, 0.f);
        a2 += fmaxf((float)v.z * sc.z + sh.z, 0.f);
        a3 += fmaxf((float)v.w * sc.w + sh.w, 0.f);
    }
    half4 o;
    o.x = (_Float16)a0; o.y = (_Float16)a1;
    o.z = (_Float16)a2; o.w = (_Float16)a3;
    ((half4*)(z + (size_t)node * DIM))[lane] = o;
}

// ---------------------------------------------------------------------------
// GEMM1: C = A @ Wt^T + bias, fused BN col stats. (A read as-is.)
// ---------------------------------------------------------------------------
__global__ __launch_bounds__(256) void gemm_f16(const _Float16* __restrict__ A,
                                                const _Float16* __restrict__ Wt,
                                                const float* __restrict__ bias,
                                                _Float16* __restrict__ C,
                                                float* __restrict__ stats,
                                                int M) {
    __shared__ _Float16 Asm[128 * 32];
    __shared__ _Float16 Bsm[128 * 32];
    __shared__ float colsum[128];
    __shared__ float colsq[128];

    int tid = threadIdx.x;
    int wid = tid >> 6, lane = tid & 63;
    int quad = lane >> 4, lrow = lane & 15;
    int row0 = blockIdx.y * 128, col0 = blockIdx.x * 128;
    int wm = (wid & 1) * 64, wn = (wid >> 1) * 64;

    if (tid < 128) { colsum[tid] = 0.0f; colsq[tid] = 0.0f; }

    f32x4 acc[4][4] = {};
    const char* Ab = (const char*)A;
    const char* Bb = (const char*)Wt;

    for (int k0 = 0; k0 < DIM; k0 += 32) {
#pragma unroll
        for (int j = 0; j < 2; j++) {
            int b = wid * 2048 + j * 1024 + lane * 16;
            int m = b >> 6;
            int kb = b & 63;
            async16(Ab + (size_t)(row0 + m) * 512 + k0 * 2 + kb,
                    (char*)Asm + wid * 2048 + j * 1024);
            async16(Bb + (size_t)(col0 + m) * 512 + k0 * 2 + kb,
                    (char*)Bsm + wid * 2048 + j * 1024);
        }
        __syncthreads();

        half8 af[4], bf[4];
#pragma unroll
        for (int t = 0; t < 4; t++) {
            af[t] = *(const half8*)(Asm + (wm + t * 16 + lrow) * 32 + quad * 8);
            bf[t] = *(const half8*)(Bsm + (wn + t * 16 + lrow) * 32 + quad * 8);
        }
#pragma unroll
        for (int i = 0; i < 4; i++)
#pragma unroll
            for (int j = 0; j < 4; j++)
                acc[i][j] = __builtin_amdgcn_mfma_f32_16x16x32_f16(
                    af[i], bf[j], acc[i][j], 0, 0, 0);
        __syncthreads();
    }

    float bcol[4];
#pragma unroll
    for (int j = 0; j < 4; j++) bcol[j] = bias[col0 + wn + j * 16 + lrow];

    float csum[4] = {0.f, 0.f, 0.f, 0.f};
    float csq[4] = {0.f, 0.f, 0.f, 0.f};
#pragma unroll
    for (int i = 0; i < 4; i++) {
        int rbase = row0 + wm + i * 16 + quad * 4;
#pragma unroll
        for (int j = 0; j < 4; j++) {
            int col = col0 + wn + j * 16 + lrow;
#pragma unroll
            for (int r = 0; r < 4; r++) {
                int row = rbase + r;
                if (row < M) {
                    float v = acc[i][j][r] + bcol[j];
                    C[(size_t)row * DIM + col] = (_Float16)v;
                    csum[j] += v;
                    csq[j] += v * v;
                }
            }
        }
    }
#pragma unroll
    for (int j = 0; j < 4; j++) {
        atomicAdd(&colsum[wn + j * 16 + lrow], csum[j]);
        atomicAdd(&colsq[wn + j * 16 + lrow], csq[j]);
    }
    __syncthreads();
    if (tid < 128) {
        atomicAdd(&stats[col0 + tid], colsum[tid]);
        atomicAdd(&stats[DIM + col0 + tid], colsq[tid]);
    }
}

// ---------------------------------------------------------------------------
// GEMM2 with fused input BN1+ReLU: reads RAW GEMM1 output; A-fragments are
// transformed a' = relu(a*sc[k] + sh[k]) with packed fp16 math before MFMA.
// sc/sh staged in LDS (fp16).
// ---------------------------------------------------------------------------
__global__ __launch_bounds__(256) void gemm_bn(const _Float16* __restrict__ A,
                                               const _Float16* __restrict__ Wt,
                                               const float* __restrict__ bias,
                                               const float* __restrict__ scsh,
                                               _Float16* __restrict__ C,
                                               float* __restrict__ stats,
                                               int M) {
    __shared__ _Float16 Asm[128 * 32];
    __shared__ _Float16 Bsm[128 * 32];
    __shared__ _Float16 scs[DIM];
    __shared__ _Float16 shs[DIM];
    __shared__ float colsum[128];
    __shared__ float colsq[128];

    int tid = threadIdx.x;
    int wid = tid >> 6, lane = tid & 63;
    int quad = lane >> 4, lrow = lane & 15;
    int row0 = blockIdx.y * 128, col0 = blockIdx.x * 128;
    int wm = (wid & 1) * 64, wn = (wid >> 1) * 64;

    scs[tid] = (_Float16)scsh[tid];
    shs[tid] = (_Float16)scsh[DIM + tid];
    if (tid < 128) { colsum[tid] = 0.0f; colsq[tid] = 0.0f; }

    f32x4 acc[4][4] = {};
    const char* Ab = (const char*)A;
    const char* Bb = (const char*)Wt;
    const half8 zerov = {0, 0, 0, 0, 0, 0, 0, 0};

    for (int k0 = 0; k0 < DIM; k0 += 32) {
#pragma unroll
        for (int j = 0; j < 2; j++) {
            int b = wid * 2048 + j * 1024 + lane * 16;
            int m = b >> 6;
            int kb = b & 63;
            async16(Ab + (size_t)(row0 + m) * 512 + k0 * 2 + kb,
                    (char*)Asm + wid * 2048 + j * 1024);
            async16(Bb + (size_t)(col0 + m) * 512 + k0 * 2 + kb,
                    (char*)Bsm + wid * 2048 + j * 1024);
        }
        __syncthreads();   // also covers scs/shs stores on first iteration

        half8 scv = *(const half8*)(scs + k0 + quad * 8);
        half8 shv = *(const half8*)(shs + k0 + quad * 8);

        half8 af[4], bf[4];
#pragma unroll
        for (int t = 0; t < 4; t++) {
            half8 a = *(const half8*)(Asm + (wm + t * 16 + lrow) * 32 + quad * 8);
            af[t] = __builtin_elementwise_max(a * scv + shv, zerov);  // v_pk_fma/max
            bf[t] = *(const half8*)(Bsm + (wn + t * 16 + lrow) * 32 + quad * 8);
        }
#pragma unroll
        for (int i = 0; i < 4; i++)
#pragma unroll
            for (int j = 0; j < 4; j++)
                acc[i][j] = __builtin_amdgcn_mfma_f32_16x16x32_f16(
                    af[i], bf[j], acc[i][j], 0, 0, 0);
        __syncthreads();
    }

    float bcol[4];
#pragma unroll
    for (int j = 0; j < 4; j++) bcol[j] = bias[col0 + wn + j * 16 + lrow];

    float csum[4] = {0.f, 0.f, 0.f, 0.f};
    float csq[4] = {0.f, 0.f, 0.f, 0.f};
#pragma unroll
    for (int i = 0; i < 4; i++) {
        int rbase = row0 + wm + i * 16 + quad * 4;
#pragma unroll
        for (int j = 0; j < 4; j++) {
            int col = col0 + wn + j * 16 + lrow;
#pragma unroll
            for (int r = 0; r < 4; r++) {
                int row = rbase + r;
                if (row < M) {
                    float v = acc[i][j][r] + bcol[j];
                    C[(size_t)row * DIM + col] = (_Float16)v;
                    csum[j] += v;
                    csq[j] += v * v;
                }
            }
        }
    }
#pragma unroll
    for (int j = 0; j < 4; j++) {
        atomicAdd(&colsum[wn + j * 16 + lrow], csum[j]);
        atomicAdd(&colsq[wn + j * 16 + lrow], csq[j]);
    }
    __syncthreads();
    if (tid < 128) {
        atomicAdd(&stats[col0 + tid], colsum[tid]);
        atomicAdd(&stats[DIM + col0 + tid], colsq[tid]);
    }
}

// ---------------------------------------------------------------------------
// Finalize BN; zeroes its stats buffer for the next layer's accumulation.
// ---------------------------------------------------------------------------
__global__ __launch_bounds__(256) void bn_finalize(float* __restrict__ stats,
                                                   const float* __restrict__ g,
                                                   const float* __restrict__ beta,
                                                   float* __restrict__ scsh,
                                                   int n) {
    int d = threadIdx.x;
    float invn = 1.0f / (float)n;
    float mean = stats[d] * invn;
    float var = stats[DIM + d] * invn - mean * mean;
    float inv = rsqrtf(var + 1e-5f);
    float scale = g[d] * inv;
    scsh[d] = scale;
    scsh[DIM + d] = beta[d] - mean * scale;
    stats[d] = 0.0f;
    stats[DIM + d] = 0.0f;
}

// ---------------------------------------------------------------------------
// Final BN apply (layer 4): no relu, fp32 out.
// ---------------------------------------------------------------------------
__global__ __launch_bounds__(256) void bn_apply_f(const _Float16* __restrict__ in,
                                                  float* __restrict__ outf,
                                                  const float* __restrict__ scsh) {
    size_t i = (size_t)blockIdx.x * 256 + threadIdx.x;
    int c4 = (int)(i & 63);
    float4 sc = ((const float4*)scsh)[c4];
    float4 sh = ((const float4*)(scsh + DIM))[c4];
    half4 v = ((const half4*)in)[i];
    float4 o;
    o.x = (float)v.x * sc.x + sh.x;
    o.y = (float)v.y * sc.y + sh.y;
    o.z = (float)v.z * sc.z + sh.z;
    o.w = (float)v.w * sc.w + sh.w;
    ((float4*)outf)[i] = o;
}

// ---------------------------------------------------------------------------
extern "C" void kernel_launch(void* const* d_in, const int* in_sizes, int n_in,
                              void* d_out, int out_size, void* d_ws, size_t ws_size,
                              hipStream_t stream) {
    (void)in_sizes; (void)n_in; (void)out_size; (void)ws_size;
    const float* x   = (const float*)d_in[0];
    const int*   src = (const int*)d_in[1];
    const int*   dst = (const int*)d_in[2];
    const float* W1  = (const float*)d_in[3];
    const float* b1  = (const float*)d_in[4];
    const float* g1  = (const float*)d_in[5];
    const float* bt1 = (const float*)d_in[6];
    const float* W2  = (const float*)d_in[7];
    const float* b2  = (const float*)d_in[8];
    const float* eps = (const float*)d_in[9];
    const float* bng = (const float*)d_in[10];
    const float* bnb = (const float*)d_in[11];
    float* out = (float*)d_out;

    const int N = N_NODES, E = N_EDGES, D = DIM;
    size_t NDp = (size_t)MPAD * D;

    _Float16* gin  = (_Float16*)d_ws;              // gather output / GEMM1 in
    _Float16* C1   = gin + NDp;                    // GEMM1 raw out (also xh @ l0)
    _Float16* C2   = C1 + NDp;                     // GEMM2 raw out
    _Float16* Wt   = C2 + NDp;                     // 10 * 256*256 fp16
    float* stats = (float*)(Wt + 10 * 65536);      // 1024 f (2 sets of 512)
    float* scshA = stats + 1024;                   // 512 f (BN1)
    float* scshB = scshA + 512;                    // 512 f (BN2)
    int* deg     = (int*)(scshB + 512);            // N (cursor)
    int* ptr     = deg + N;                        // N+1
    int* bsum    = ptr + N + 1;                    // 64
    int* srcbuf  = bsum + 64;                      // E

    const int ELEM4_BLOCKS = N * D / 4 / 256;      // 12500
    const int NODE_BLOCKS  = (N + 3) / 4;          // 12500
    const int E_BLOCKS     = (E + 255) / 256;      // 1172
    const int SCAN_BLOCKS  = (N + 1023) / 1024;    // 49
    const dim3 GEMM_GRID(2, MPAD / 128);           // (2, 391)

    // ---- One-time per call: CSR build, stats zero, conversions ----
    hipMemsetAsync(deg, 0, N * sizeof(int), stream);
    hipMemsetAsync(stats, 0, 1024 * sizeof(float), stream);
    hist_dst<<<E_BLOCKS, 256, 0, stream>>>(dst, deg, E);
    scan_blk<<<SCAN_BLOCKS, 1024, 0, stream>>>(deg, ptr, bsum, N);
    scan_top<<<1, 64, 0, stream>>>(bsum, ptr, SCAN_BLOCKS, N, E);
    scan_add<<<SCAN_BLOCKS, 1024, 0, stream>>>(ptr, bsum, deg, N);
    scatter_src<<<E_BLOCKS, 256, 0, stream>>>(src, dst, deg, srcbuf, E);
    wconv<<<160, 256, 0, stream>>>(W1, W2, Wt);
    x2h<<<ELEM4_BLOCKS, 256, 0, stream>>>(x, C1);  // C1 = xh for layer 0

    for (int l = 0; l < 5; l++) {
        // Gather (+ fused BN2-of-previous-layer for l>=1) -> gin (fp16)
        if (l == 0)
            gather_h<<<NODE_BLOCKS, 256, 0, stream>>>(C1, ptr, srcbuf, gin, eps);
        else
            gather_bn<<<NODE_BLOCKS, 256, 0, stream>>>(C2, ptr, srcbuf, gin,
                                                       scshB, eps, l);

        // C1 = gin @ W1 + b1 (raw), fused BN1 stats
        gemm_f16<<<GEMM_GRID, 256, 0, stream>>>(
            gin, Wt + (size_t)l * 65536, b1 + (size_t)l * D, C1, stats, N);
        bn_finalize<<<1, 256, 0, stream>>>(stats, g1 + (size_t)l * D,
                                           bt1 + (size_t)l * D, scshA, N);

        // C2 = relu(BN1(C1)) @ W2 + b2 (raw), fused BN2 stats
        gemm_bn<<<GEMM_GRID, 256, 0, stream>>>(
            C1, Wt + (size_t)(5 + l) * 65536, b2 + (size_t)l * D, scshA,
            C2, stats + 512, N);
        bn_finalize<<<1, 256, 0, stream>>>(stats + 512, bng + (size_t)l * D,
                                           bnb + (size_t)l * D, scshB, N);

        // BN2 consumed fused in next layer's gather; final layer writes out.
        if (l == 4)
            bn_apply_f<<<ELEM4_BLOCKS, 256, 0, stream>>>(C2, out, scshB);
    }
}

// Round 7
// 727.697 us; speedup vs baseline: 9.1789x; 1.0255x over previous
//
#include <hip/hip_runtime.h>
#include <hip/hip_bf16.h>

#define N_NODES 50000
#define N_EDGES 300000
#define DIM 256
#define MPAD 50048   // 391 * 128

typedef __attribute__((ext_vector_type(8))) _Float16 half8;
typedef __attribute__((ext_vector_type(4))) _Float16 half4;
typedef __attribute__((ext_vector_type(4))) float f32x4;

__device__ __forceinline__ void async16(const void* g, void* l) {
    __builtin_amdgcn_global_load_lds(
        (const __attribute__((address_space(1))) unsigned int*)g,
        (__attribute__((address_space(3))) unsigned int*)l, 16, 0, 0);
}

// ---------------------------------------------------------------------------
// CSR build: histogram
// ---------------------------------------------------------------------------
__global__ __launch_bounds__(256) void hist_dst(const int* __restrict__ dst,
                                                int* __restrict__ deg, int E) {
    int e = blockIdx.x * blockDim.x + threadIdx.x;
    if (e < E) atomicAdd(&deg[dst[e]], 1);
}

// ---------------------------------------------------------------------------
// Hierarchical scan, step 1: per-block (1024) exclusive scan via wave shuffles.
// ---------------------------------------------------------------------------
__global__ __launch_bounds__(1024) void scan_blk(const int* __restrict__ deg,
                                                 int* __restrict__ ptr,
                                                 int* __restrict__ bsum, int n) {
    __shared__ int wsum[16];
    __shared__ int wpre[16];
    int tid = threadIdx.x;
    int i = blockIdx.x * 1024 + tid;
    int v = (i < n) ? deg[i] : 0;
    int lane = tid & 63, w = tid >> 6;
    int s = v;
#pragma unroll
    for (int off = 1; off < 64; off <<= 1) {
        int t = __shfl_up(s, off, 64);
        if (lane >= off) s += t;
    }
    if (lane == 63) wsum[w] = s;
    __syncthreads();
    if (tid < 16) {
        int acc = 0;
        for (int j = 0; j < tid; j++) acc += wsum[j];
        wpre[tid] = acc;
    }
    __syncthreads();
    int incl = s + wpre[w];
    if (i < n) ptr[i] = incl - v;
    if (tid == 1023) bsum[blockIdx.x] = incl;
}

// ---------------------------------------------------------------------------
// Scan step 2: single wave scans block totals (nb <= 64).
// ---------------------------------------------------------------------------
__global__ __launch_bounds__(64) void scan_top(int* __restrict__ bsum,
                                               int* __restrict__ ptr,
                                               int nb, int n, int E) {
    int lane = threadIdx.x;
    int v = (lane < nb) ? bsum[lane] : 0;
    int s = v;
#pragma unroll
    for (int off = 1; off < 64; off <<= 1) {
        int t = __shfl_up(s, off, 64);
        if (lane >= off) s += t;
    }
    if (lane < nb) bsum[lane] = s - v;
    if (lane == 0) ptr[n] = E;
}

// ---------------------------------------------------------------------------
// Scan step 3: add block offset; duplicate into cursor.
// ---------------------------------------------------------------------------
__global__ __launch_bounds__(1024) void scan_add(int* __restrict__ ptr,
                                                 const int* __restrict__ bsum,
                                                 int* __restrict__ cursor, int n) {
    int i = blockIdx.x * 1024 + threadIdx.x;
    if (i < n) {
        int val = ptr[i] + bsum[blockIdx.x];
        ptr[i] = val;
        cursor[i] = val;
    }
}

// ---------------------------------------------------------------------------
// CSR build: counting-sort scatter
// ---------------------------------------------------------------------------
__global__ __launch_bounds__(256) void scatter_src(const int* __restrict__ src,
                                                   const int* __restrict__ dst,
                                                   int* __restrict__ cursor,
                                                   int* __restrict__ srcbuf, int E) {
    int e = blockIdx.x * blockDim.x + threadIdx.x;
    if (e < E) {
        int pos = atomicAdd(&cursor[dst[e]], 1);
        srcbuf[pos] = src[e];
    }
}

// ---------------------------------------------------------------------------
// x (fp32) -> fp16
// ---------------------------------------------------------------------------
__global__ __launch_bounds__(256) void x2h(const float* __restrict__ x,
                                           _Float16* __restrict__ hb) {
    size_t i = (size_t)blockIdx.x * 256 + threadIdx.x;  // float4 index
    float4 v = ((const float4*)x)[i];
    half4 o;
    o.x = (_Float16)v.x; o.y = (_Float16)v.y;
    o.z = (_Float16)v.z; o.w = (_Float16)v.w;
    ((half4*)hb)[i] = o;
}

// ---------------------------------------------------------------------------
// W (fp32, [K][N] row-major) -> Wt (fp16, [N][K]) for 10 matrices
// ---------------------------------------------------------------------------
__global__ __launch_bounds__(256) void wconv(const float* __restrict__ W1,
                                             const float* __restrict__ W2,
                                             _Float16* __restrict__ Wt) {
    int mat = blockIdx.x >> 4;
    int t = blockIdx.x & 15;
    int tr = t >> 2, tc = t & 3;
    const float* W = (mat < 5) ? (W1 + (size_t)mat * 65536)
                               : (W2 + (size_t)(mat - 5) * 65536);
    __shared__ float tile[64][65];
    int tid = threadIdx.x;
    int c = tid & 63, r0 = tid >> 6;
#pragma unroll 4
    for (int i = 0; i < 16; i++) {
        int r = r0 + i * 4;
        tile[r][c] = W[(size_t)(tr * 64 + r) * 256 + tc * 64 + c];
    }
    __syncthreads();
    _Float16* o = Wt + (size_t)mat * 65536;
#pragma unroll 4
    for (int i = 0; i < 16; i++) {
        int r = r0 + i * 4;
        o[(size_t)(tc * 64 + r) * 256 + tr * 64 + c] = (_Float16)tile[c][r];
    }
}

// ---------------------------------------------------------------------------
// Layer-0 gather (fp16 x): z[n] = (1+eps)*xh[n] + sum relu(xh[src]).
// ---------------------------------------------------------------------------
__global__ __launch_bounds__(256) void gather_h(const _Float16* __restrict__ h,
                                                const int* __restrict__ ptr,
                                                const int* __restrict__ srcbuf,
                                                _Float16* __restrict__ z,
                                                const float* __restrict__ eps) {
    int node = blockIdx.x * 4 + (threadIdx.x >> 6);
    if (node >= N_NODES) return;
    int lane = threadIdx.x & 63;
    int beg = ptr[node], end = ptr[node + 1];
    float s = 1.0f + eps[0];
    half4 hv = ((const half4*)(h + (size_t)node * DIM))[lane];
    float a0 = (float)hv.x * s, a1 = (float)hv.y * s;
    float a2 = (float)hv.z * s, a3 = (float)hv.w * s;
    int e = beg;
    for (; e + 4 <= end; e += 4) {
        int s0 = srcbuf[e], s1 = srcbuf[e + 1], s2 = srcbuf[e + 2], s3 = srcbuf[e + 3];
        half4 v0 = ((const half4*)(h + (size_t)s0 * DIM))[lane];
        half4 v1 = ((const half4*)(h + (size_t)s1 * DIM))[lane];
        half4 v2 = ((const half4*)(h + (size_t)s2 * DIM))[lane];
        half4 v3 = ((const half4*)(h + (size_t)s3 * DIM))[lane];
        a0 += fmaxf((float)v0.x, 0.f) + fmaxf((float)v1.x, 0.f)
            + fmaxf((float)v2.x, 0.f) + fmaxf((float)v3.x, 0.f);
        a1 += fmaxf((float)v0.y, 0.f) + fmaxf((float)v1.y, 0.f)
            + fmaxf((float)v2.y, 0.f) + fmaxf((float)v3.y, 0.f);
        a2 += fmaxf((float)v0.z, 0.f) + fmaxf((float)v1.z, 0.f)
            + fmaxf((float)v2.z, 0.f) + fmaxf((float)v3.z, 0.f);
        a3 += fmaxf((float)v0.w, 0.f) + fmaxf((float)v1.w, 0.f)
            + fmaxf((float)v2.w, 0.f) + fmaxf((float)v3.w, 0.f);
    }
    for (; e < end; e++) {
        half4 v = ((const half4*)(h + (size_t)srcbuf[e] * DIM))[lane];
        a0 += fmaxf((float)v.x, 0.f); a1 += fmaxf((float)v.y, 0.f);
        a2 += fmaxf((float)v.z, 0.f); a3 += fmaxf((float)v.w, 0.f);
    }
    half4 o;
    o.x = (_Float16)a0; o.y = (_Float16)a1;
    o.z = (_Float16)a2; o.w = (_Float16)a3;
    ((half4*)(z + (size_t)node * DIM))[lane] = o;
}

// ---------------------------------------------------------------------------
// Layers 1..4 gather with fused BN2: h = relu(scale*C + shift) on the fly.
// ---------------------------------------------------------------------------
__global__ __launch_bounds__(256) void gather_bn(const _Float16* __restrict__ C,
                                                 const int* __restrict__ ptr,
                                                 const int* __restrict__ srcbuf,
                                                 _Float16* __restrict__ z,
                                                 const float* __restrict__ scsh,
                                                 const float* __restrict__ eps,
                                                 int l) {
    int node = blockIdx.x * 4 + (threadIdx.x >> 6);
    if (node >= N_NODES) return;
    int lane = threadIdx.x & 63;
    float4 sc = ((const float4*)scsh)[lane];
    float4 sh = ((const float4*)(scsh + DIM))[lane];
    int beg = ptr[node], end = ptr[node + 1];
    float s = 1.0f + eps[l];
    half4 hv = ((const half4*)(C + (size_t)node * DIM))[lane];
    float a0 = s * fmaxf((float)hv.x * sc.x + sh.x, 0.f);
    float a1 = s * fmaxf((float)hv.y * sc.y + sh.y, 0.f);
    float a2 = s * fmaxf((float)hv.z * sc.z + sh.z, 0.f);
    float a3 = s * fmaxf((float)hv.w * sc.w + sh.w, 0.f);
    int e = beg;
    for (; e + 4 <= end; e += 4) {
        int s0 = srcbuf[e], s1 = srcbuf[e + 1], s2 = srcbuf[e + 2], s3 = srcbuf[e + 3];
        half4 v0 = ((const half4*)(C + (size_t)s0 * DIM))[lane];
        half4 v1 = ((const half4*)(C + (size_t)s1 * DIM))[lane];
        half4 v2 = ((const half4*)(C + (size_t)s2 * DIM))[lane];
        half4 v3 = ((const half4*)(C + (size_t)s3 * DIM))[lane];
        a0 += fmaxf((float)v0.x * sc.x + sh.x, 0.f) + fmaxf((float)v1.x * sc.x + sh.x, 0.f)
            + fmaxf((float)v2.x * sc.x + sh.x, 0.f) + fmaxf((float)v3.x * sc.x + sh.x, 0.f);
        a1 += fmaxf((float)v0.y * sc.y + sh.y, 0.f) + fmaxf((float)v1.y * sc.y + sh.y, 0.f)
            + fmaxf((float)v2.y * sc.y + sh.y, 0.f) + fmaxf((float)v3.y * sc.y + sh.y, 0.f);
        a2 += fmaxf((float)v0.z * sc.z + sh.z, 0.f) + fmaxf((float)v1.z * sc.z + sh.z, 0.f)
            + fmaxf((float)v2.z * sc.z + sh.z, 0.f) + fmaxf((float)v3.z * sc.z + sh.z, 0.f);
        a3 += fmaxf((float)v0.w * sc.w + sh.w, 0.f) + fmaxf((float)v1.w * sc.w + sh.w, 0.f)
            + fmaxf((float)v2.w * sc.w + sh.w, 0.f) + fmaxf((float)v3.w * sc.w + sh.w, 0.f);
    }
    for (; e < end; e++) {
        half4 v = ((const half4*)(C + (size_t)srcbuf[e] * DIM))[lane];
        a0 += fmaxf((float)v.x * sc.x + sh.x, 0.f);
        a1 += fmaxf((float)v.y * sc.y + sh.y, 0.f);
        a2 += fmaxf((float)v.z * sc.z + sh.z, 0.f);
        a3 += fmaxf((float)v.w * sc.w + sh.w, 0.f);
    }
    half4 o;
    o.x = (_Float16)a0; o.y = (_Float16)a1;
    o.z = (_Float16)a2; o.w = (_Float16)a3;
    ((half4*)(z + (size_t)node * DIM))[lane] = o;
}

// ===========================================================================
// GEMM: 128x128 tile, BK=128 (2 K-iterations only), XOR-swizzled LDS.
//
// LDS layout: 16B chunk c (0..15) of tile row m stored at chunk slot
// m*16 + (c ^ (m&7)). Staging picks each lane's GLOBAL source to match
// (global_load_lds writes lane i at base+i*16, so LDS side stays linear).
// Fragment reads then hit all 8 bank groups 2-way (free).
// A-tile at smem[0..32KB), B-tile at [32KB..64KB); colsum/colsq alias the
// A-tile after compute. Total static LDS = 64 KB -> 2 blocks/CU.
// ===========================================================================
#define GEMM_EPILOGUE(DOSTATS)                                               \
    __syncthreads();                                                         \
    float* colsum = (float*)smem;                                            \
    float* colsq = colsum + 128;                                             \
    if (tid < 128) { colsum[tid] = 0.0f; colsq[tid] = 0.0f; }                \
    __syncthreads();                                                         \
    float bcol[4];                                                           \
    _Pragma("unroll")                                                        \
    for (int j = 0; j < 4; j++) bcol[j] = bias[col0 + wn + j * 16 + lrow];   \
    float csum[4] = {0.f, 0.f, 0.f, 0.f};                                    \
    float csq[4] = {0.f, 0.f, 0.f, 0.f};                                     \
    _Pragma("unroll")                                                        \
    for (int i = 0; i < 4; i++) {                                            \
        int rbase = row0 + wm + i * 16 + quad * 4;                           \
        _Pragma("unroll")                                                    \
        for (int j = 0; j < 4; j++) {                                        \
            int col = col0 + wn + j * 16 + lrow;                             \
            _Pragma("unroll")                                                \
            for (int r = 0; r < 4; r++) {                                    \
                int row = rbase + r;                                         \
                if (row < M) {                                               \
                    float v = acc[i][j][r] + bcol[j];                        \
                    C[(size_t)row * DIM + col] = (_Float16)v;                \
                    csum[j] += v;                                            \
                    csq[j] += v * v;                                         \
                }                                                            \
            }                                                                \
        }                                                                    \
    }                                                                        \
    _Pragma("unroll")                                                        \
    for (int j = 0; j < 4; j++) {                                            \
        atomicAdd(&colsum[wn + j * 16 + lrow], csum[j]);                     \
        atomicAdd(&colsq[wn + j * 16 + lrow], csq[j]);                       \
    }                                                                        \
    __syncthreads();                                                         \
    if (tid < 128) {                                                         \
        atomicAdd(&stats[col0 + tid], colsum[tid]);                          \
        atomicAdd(&stats[DIM + col0 + tid], colsq[tid]);                     \
    }

__global__ __launch_bounds__(256) void gemm_f16(const _Float16* __restrict__ A,
                                                const _Float16* __restrict__ Wt,
                                                const float* __restrict__ bias,
                                                _Float16* __restrict__ C,
                                                float* __restrict__ stats,
                                                int M) {
    __shared__ uint4 smem[4096];  // 64 KB: A-tile 32K | B-tile 32K

    int tid = threadIdx.x;
    int wid = tid >> 6, lane = tid & 63;
    int quad = lane >> 4, lrow = lane & 15;
    int row0 = blockIdx.y * 128, col0 = blockIdx.x * 128;
    int wm = (wid & 1) * 64, wn = (wid >> 1) * 64;

    f32x4 acc[4][4] = {};
    const char* Ab = (const char*)A;
    const char* Bb = (const char*)Wt;

#pragma unroll
    for (int ko = 0; ko < 2; ko++) {
        int kb0 = ko * 256;  // byte offset of this K-half within a 512B row
        // Stage: 8 A-instrs + 8 B-instrs per wave, swizzled source pick
#pragma unroll
        for (int j = 0; j < 8; j++) {
            int sbase = wid * 512 + j * 64;   // 16B-slot base (wave-uniform)
            int s = sbase + lane;
            int m = s >> 4;
            int c = (s & 15) ^ (m & 7);
            size_t go = (size_t)(row0 + m) * 512 + kb0 + c * 16;
            async16(Ab + go, (char*)smem + sbase * 16);
            size_t gob = (size_t)(col0 + m) * 512 + kb0 + c * 16;
            async16(Bb + gob, (char*)smem + 32768 + sbase * 16);
        }
        __syncthreads();
#pragma unroll
        for (int kc = 0; kc < 4; kc++) {
            half8 af[4], bf[4];
#pragma unroll
            for (int t = 0; t < 4; t++) {
                int ma = wm + t * 16 + lrow;
                int ca = kc * 4 + quad;
                af[t] = *(const half8*)((const char*)smem +
                                        (ma * 16 + (ca ^ (ma & 7))) * 16);
                int mb = wn + t * 16 + lrow;
                bf[t] = *(const half8*)((const char*)smem + 32768 +
                                        (mb * 16 + (ca ^ (mb & 7))) * 16);
            }
#pragma unroll
            for (int i = 0; i < 4; i++)
#pragma unroll
                for (int j2 = 0; j2 < 4; j2++)
                    acc[i][j2] = __builtin_amdgcn_mfma_f32_16x16x32_f16(
                        af[i], bf[j2], acc[i][j2], 0, 0, 0);
        }
        if (ko == 0) __syncthreads();
    }

    GEMM_EPILOGUE(1)
}

// Same GEMM with fused input BN1+ReLU (scale/shift held in registers).
__global__ __launch_bounds__(256) void gemm_bn(const _Float16* __restrict__ A,
                                               const _Float16* __restrict__ Wt,
                                               const float* __restrict__ bias,
                                               const float* __restrict__ scsh,
                                               _Float16* __restrict__ C,
                                               float* __restrict__ stats,
                                               int M) {
    __shared__ uint4 smem[4096];  // 64 KB

    int tid = threadIdx.x;
    int wid = tid >> 6, lane = tid & 63;
    int quad = lane >> 4, lrow = lane & 15;
    int row0 = blockIdx.y * 128, col0 = blockIdx.x * 128;
    int wm = (wid & 1) * 64, wn = (wid >> 1) * 64;

    // Per-lane BN1 scale/shift fragments for all 8 k-chunks (fp16, regs)
    half8 scv[8], shv[8];
#pragma unroll
    for (int cc = 0; cc < 8; cc++) {
        int kk = cc * 32 + quad * 8;
        float4 s0 = *(const float4*)(scsh + kk);
        float4 s1 = *(const float4*)(scsh + kk + 4);
        float4 h0 = *(const float4*)(scsh + DIM + kk);
        float4 h1 = *(const float4*)(scsh + DIM + kk + 4);
        half8 sv = {(_Float16)s0.x, (_Float16)s0.y, (_Float16)s0.z, (_Float16)s0.w,
                    (_Float16)s1.x, (_Float16)s1.y, (_Float16)s1.z, (_Float16)s1.w};
        half8 hv = {(_Float16)h0.x, (_Float16)h0.y, (_Float16)h0.z, (_Float16)h0.w,
                    (_Float16)h1.x, (_Float16)h1.y, (_Float16)h1.z, (_Float16)h1.w};
        scv[cc] = sv;
        shv[cc] = hv;
    }

    f32x4 acc[4][4] = {};
    const char* Ab = (const char*)A;
    const char* Bb = (const char*)Wt;
    const half8 zerov = {0, 0, 0, 0, 0, 0, 0, 0};

#pragma unroll
    for (int ko = 0; ko < 2; ko++) {
        int kb0 = ko * 256;
#pragma unroll
        for (int j = 0; j < 8; j++) {
            int sbase = wid * 512 + j * 64;
            int s = sbase + lane;
            int m = s >> 4;
            int c = (s & 15) ^ (m & 7);
            size_t go = (size_t)(row0 + m) * 512 + kb0 + c * 16;
            async16(Ab + go, (char*)smem + sbase * 16);
            size_t gob = (size_t)(col0 + m) * 512 + kb0 + c * 16;
            async16(Bb + gob, (char*)smem + 32768 + sbase * 16);
        }
        __syncthreads();
#pragma unroll
        for (int kc = 0; kc < 4; kc++) {
            half8 af[4], bf[4];
            half8 sv = scv[ko * 4 + kc];
            half8 hv = shv[ko * 4 + kc];
#pragma unroll
            for (int t = 0; t < 4; t++) {
                int ma = wm + t * 16 + lrow;
                int ca = kc * 4 + quad;
                half8 a = *(const half8*)((const char*)smem +
                                          (ma * 16 + (ca ^ (ma & 7))) * 16);
                af[t] = __builtin_elementwise_max(a * sv + hv, zerov);
                int mb = wn + t * 16 + lrow;
                bf[t] = *(const half8*)((const char*)smem + 32768 +
                                        (mb * 16 + (ca ^ (mb & 7))) * 16);
            }
#pragma unroll
            for (int i = 0; i < 4; i++)
#pragma unroll
                for (int j2 = 0; j2 < 4; j2++)
                    acc[i][j2] = __builtin_amdgcn_mfma_f32_16x16x32_f16(
                        af[i], bf[j2], acc[i][j2], 0, 0, 0);
        }
        if (ko == 0) __syncthreads();
    }

    GEMM_EPILOGUE(1)
}

// ---------------------------------------------------------------------------
// Finalize BN; zeroes its stats buffer for the next layer's accumulation.
// ---------------------------------------------------------------------------
__global__ __launch_bounds__(256) void bn_finalize(float* __restrict__ stats,
                                                   const float* __restrict__ g,
                                                   const float* __restrict__ beta,
                                                   float* __restrict__ scsh,
                                                   int n) {
    int d = threadIdx.x;
    float invn = 1.0f / (float)n;
    float mean = stats[d] * invn;
    float var = stats[DIM + d] * invn - mean * mean;
    float inv = rsqrtf(var + 1e-5f);
    float scale = g[d] * inv;
    scsh[d] = scale;
    scsh[DIM + d] = beta[d] - mean * scale;
    stats[d] = 0.0f;
    stats[DIM + d] = 0.0f;
}

// ---------------------------------------------------------------------------
// Final BN apply (layer 4): no relu, fp32 out.
// ---------------------------------------------------------------------------
__global__ __launch_bounds__(256) void bn_apply_f(const _Float16* __restrict__ in,
                                                  float* __restrict__ outf,
                                                  const float* __restrict__ scsh) {
    size_t i = (size_t)blockIdx.x * 256 + threadIdx.x;
    int c4 = (int)(i & 63);
    float4 sc = ((const float4*)scsh)[c4];
    float4 sh = ((const float4*)(scsh + DIM))[c4];
    half4 v = ((const half4*)in)[i];
    float4 o;
    o.x = (float)v.x * sc.x + sh.x;
    o.y = (float)v.y * sc.y + sh.y;
    o.z = (float)v.z * sc.z + sh.z;
    o.w = (float)v.w * sc.w + sh.w;
    ((float4*)outf)[i] = o;
}

// ---------------------------------------------------------------------------
extern "C" void kernel_launch(void* const* d_in, const int* in_sizes, int n_in,
                              void* d_out, int out_size, void* d_ws, size_t ws_size,
                              hipStream_t stream) {
    (void)in_sizes; (void)n_in; (void)out_size; (void)ws_size;
    const float* x   = (const float*)d_in[0];
    const int*   src = (const int*)d_in[1];
    const int*   dst = (const int*)d_in[2];
    const float* W1  = (const float*)d_in[3];
    const float* b1  = (const float*)d_in[4];
    const float* g1  = (const float*)d_in[5];
    const float* bt1 = (const float*)d_in[6];
    const float* W2  = (const float*)d_in[7];
    const float* b2  = (const float*)d_in[8];
    const float* eps = (const float*)d_in[9];
    const float* bng = (const float*)d_in[10];
    const float* bnb = (const float*)d_in[11];
    float* out = (float*)d_out;

    const int N = N_NODES, E = N_EDGES, D = DIM;
    size_t NDp = (size_t)MPAD * D;

    _Float16* gin  = (_Float16*)d_ws;              // gather output / GEMM1 in
    _Float16* C1   = gin + NDp;                    // GEMM1 raw out (also xh @ l0)
    _Float16* C2   = C1 + NDp;                     // GEMM2 raw out
    _Float16* Wt   = C2 + NDp;                     // 10 * 256*256 fp16
    float* stats = (float*)(Wt + 10 * 65536);      // 1024 f (2 sets of 512)
    float* scshA = stats + 1024;                   // 512 f (BN1)
    float* scshB = scshA + 512;                    // 512 f (BN2)
    int* deg     = (int*)(scshB + 512);            // N (cursor)
    int* ptr     = deg + N;                        // N+1
    int* bsum    = ptr + N + 1;                    // 64
    int* srcbuf  = bsum + 64;                      // E

    const int ELEM4_BLOCKS = N * D / 4 / 256;      // 12500
    const int NODE_BLOCKS  = (N + 3) / 4;          // 12500
    const int E_BLOCKS     = (E + 255) / 256;      // 1172
    const int SCAN_BLOCKS  = (N + 1023) / 1024;    // 49
    const dim3 GEMM_GRID(2, MPAD / 128);           // (2, 391)

    // ---- One-time per call: CSR build, stats zero, conversions ----
    hipMemsetAsync(deg, 0, N * sizeof(int), stream);
    hipMemsetAsync(stats, 0, 1024 * sizeof(float), stream);
    hist_dst<<<E_BLOCKS, 256, 0, stream>>>(dst, deg, E);
    scan_blk<<<SCAN_BLOCKS, 1024, 0, stream>>>(deg, ptr, bsum, N);
    scan_top<<<1, 64, 0, stream>>>(bsum, ptr, SCAN_BLOCKS, N, E);
    scan_add<<<SCAN_BLOCKS, 1024, 0, stream>>>(ptr, bsum, deg, N);
    scatter_src<<<E_BLOCKS, 256, 0, stream>>>(src, dst, deg, srcbuf, E);
    wconv<<<160, 256, 0, stream>>>(W1, W2, Wt);
    x2h<<<ELEM4_BLOCKS, 256, 0, stream>>>(x, C1);  // C1 = xh for layer 0

    for (int l = 0; l < 5; l++) {
        // Gather (+ fused BN2-of-previous-layer for l>=1) -> gin (fp16)
        if (l == 0)
            gather_h<<<NODE_BLOCKS, 256, 0, stream>>>(C1, ptr, srcbuf, gin, eps);
        else
            gather_bn<<<NODE_BLOCKS, 256, 0, stream>>>(C2, ptr, srcbuf, gin,
                                                       scshB, eps, l);

        // C1 = gin @ W1 + b1 (raw), fused BN1 stats
        gemm_f16<<<GEMM_GRID, 256, 0, stream>>>(
            gin, Wt + (size_t)l * 65536, b1 + (size_t)l * D, C1, stats, N);
        bn_finalize<<<1, 256, 0, stream>>>(stats, g1 + (size_t)l * D,
                                           bt1 + (size_t)l * D, scshA, N);

        // C2 = relu(BN1(C1)) @ W2 + b2 (raw), fused BN2 stats
        gemm_bn<<<GEMM_GRID, 256, 0, stream>>>(
            C1, Wt + (size_t)(5 + l) * 65536, b2 + (size_t)l * D, scshA,
            C2, stats + 512, N);
        bn_finalize<<<1, 256, 0, stream>>>(stats + 512, bng + (size_t)l * D,
                                           bnb + (size_t)l * D, scshB, N);

        // BN2 consumed fused in next layer's gather; final layer writes out.
        if (l == 4)
            bn_apply_f<<<ELEM4_BLOCKS, 256, 0, stream>>>(C2, out, scshB);
    }
}

// Round 8
// 661.654 us; speedup vs baseline: 10.0951x; 1.0998x over previous
//
#include <hip/hip_runtime.h>
#include <hip/hip_bf16.h>

#define N_NODES 50000
#define N_EDGES 300000
#define DIM 256
#define MPAD 50048   // 391 * 128

typedef __attribute__((ext_vector_type(8))) _Float16 half8;
typedef __attribute__((ext_vector_type(4))) _Float16 half4;
typedef __attribute__((ext_vector_type(4))) float f32x4;

__device__ __forceinline__ void async16(const void* g, void* l) {
    __builtin_amdgcn_global_load_lds(
        (const __attribute__((address_space(1))) unsigned int*)g,
        (__attribute__((address_space(3))) unsigned int*)l, 16, 0, 0);
}

// ---------------------------------------------------------------------------
// CSR build: histogram
// ---------------------------------------------------------------------------
__global__ __launch_bounds__(256) void hist_dst(const int* __restrict__ dst,
                                                int* __restrict__ deg, int E) {
    int e = blockIdx.x * blockDim.x + threadIdx.x;
    if (e < E) atomicAdd(&deg[dst[e]], 1);
}

// ---------------------------------------------------------------------------
// Hierarchical scan, step 1: per-block (1024) exclusive scan via wave shuffles.
// ---------------------------------------------------------------------------
__global__ __launch_bounds__(1024) void scan_blk(const int* __restrict__ deg,
                                                 int* __restrict__ ptr,
                                                 int* __restrict__ bsum, int n) {
    __shared__ int wsum[16];
    __shared__ int wpre[16];
    int tid = threadIdx.x;
    int i = blockIdx.x * 1024 + tid;
    int v = (i < n) ? deg[i] : 0;
    int lane = tid & 63, w = tid >> 6;
    int s = v;
#pragma unroll
    for (int off = 1; off < 64; off <<= 1) {
        int t = __shfl_up(s, off, 64);
        if (lane >= off) s += t;
    }
    if (lane == 63) wsum[w] = s;
    __syncthreads();
    if (tid < 16) {
        int acc = 0;
        for (int j = 0; j < tid; j++) acc += wsum[j];
        wpre[tid] = acc;
    }
    __syncthreads();
    int incl = s + wpre[w];
    if (i < n) ptr[i] = incl - v;
    if (tid == 1023) bsum[blockIdx.x] = incl;
}

// ---------------------------------------------------------------------------
// Scan step 2: single wave scans block totals (nb <= 64).
// ---------------------------------------------------------------------------
__global__ __launch_bounds__(64) void scan_top(int* __restrict__ bsum,
                                               int* __restrict__ ptr,
                                               int nb, int n, int E) {
    int lane = threadIdx.x;
    int v = (lane < nb) ? bsum[lane] : 0;
    int s = v;
#pragma unroll
    for (int off = 1; off < 64; off <<= 1) {
        int t = __shfl_up(s, off, 64);
        if (lane >= off) s += t;
    }
    if (lane < nb) bsum[lane] = s - v;
    if (lane == 0) ptr[n] = E;
}

// ---------------------------------------------------------------------------
// Scan step 3: add block offset; duplicate into cursor.
// ---------------------------------------------------------------------------
__global__ __launch_bounds__(1024) void scan_add(int* __restrict__ ptr,
                                                 const int* __restrict__ bsum,
                                                 int* __restrict__ cursor, int n) {
    int i = blockIdx.x * 1024 + threadIdx.x;
    if (i < n) {
        int val = ptr[i] + bsum[blockIdx.x];
        ptr[i] = val;
        cursor[i] = val;
    }
}

// ---------------------------------------------------------------------------
// CSR build: counting-sort scatter
// ---------------------------------------------------------------------------
__global__ __launch_bounds__(256) void scatter_src(const int* __restrict__ src,
                                                   const int* __restrict__ dst,
                                                   int* __restrict__ cursor,
                                                   int* __restrict__ srcbuf, int E) {
    int e = blockIdx.x * blockDim.x + threadIdx.x;
    if (e < E) {
        int pos = atomicAdd(&cursor[dst[e]], 1);
        srcbuf[pos] = src[e];
    }
}

// ---------------------------------------------------------------------------
// x (fp32) -> fp16
// ---------------------------------------------------------------------------
__global__ __launch_bounds__(256) void x2h(const float* __restrict__ x,
                                           _Float16* __restrict__ hb) {
    size_t i = (size_t)blockIdx.x * 256 + threadIdx.x;  // float4 index
    float4 v = ((const float4*)x)[i];
    half4 o;
    o.x = (_Float16)v.x; o.y = (_Float16)v.y;
    o.z = (_Float16)v.z; o.w = (_Float16)v.w;
    ((half4*)hb)[i] = o;
}

// ---------------------------------------------------------------------------
// W (fp32, [K][N] row-major) -> Wt (fp16, [N][K]) for 10 matrices
// ---------------------------------------------------------------------------
__global__ __launch_bounds__(256) void wconv(const float* __restrict__ W1,
                                             const float* __restrict__ W2,
                                             _Float16* __restrict__ Wt) {
    int mat = blockIdx.x >> 4;
    int t = blockIdx.x & 15;
    int tr = t >> 2, tc = t & 3;
    const float* W = (mat < 5) ? (W1 + (size_t)mat * 65536)
                               : (W2 + (size_t)(mat - 5) * 65536);
    __shared__ float tile[64][65];
    int tid = threadIdx.x;
    int c = tid & 63, r0 = tid >> 6;
#pragma unroll 4
    for (int i = 0; i < 16; i++) {
        int r = r0 + i * 4;
        tile[r][c] = W[(size_t)(tr * 64 + r) * 256 + tc * 64 + c];
    }
    __syncthreads();
    _Float16* o = Wt + (size_t)mat * 65536;
#pragma unroll 4
    for (int i = 0; i < 16; i++) {
        int r = r0 + i * 4;
        o[(size_t)(tc * 64 + r) * 256 + tr * 64 + c] = (_Float16)tile[c][r];
    }
}

// ---------------------------------------------------------------------------
// Layer-0 gather (fp16 x): z[n] = (1+eps)*xh[n] + sum relu(xh[src]).
// ---------------------------------------------------------------------------
__global__ __launch_bounds__(256) void gather_h(const _Float16* __restrict__ h,
                                                const int* __restrict__ ptr,
                                                const int* __restrict__ srcbuf,
                                                _Float16* __restrict__ z,
                                                const float* __restrict__ eps) {
    int node = blockIdx.x * 4 + (threadIdx.x >> 6);
    if (node >= N_NODES) return;
    int lane = threadIdx.x & 63;
    int beg = ptr[node], end = ptr[node + 1];
    float s = 1.0f + eps[0];
    half4 hv = ((const half4*)(h + (size_t)node * DIM))[lane];
    float a0 = (float)hv.x * s, a1 = (float)hv.y * s;
    float a2 = (float)hv.z * s, a3 = (float)hv.w * s;
    int e = beg;
    for (; e + 4 <= end; e += 4) {
        int s0 = srcbuf[e], s1 = srcbuf[e + 1], s2 = srcbuf[e + 2], s3 = srcbuf[e + 3];
        half4 v0 = ((const half4*)(h + (size_t)s0 * DIM))[lane];
        half4 v1 = ((const half4*)(h + (size_t)s1 * DIM))[lane];
        half4 v2 = ((const half4*)(h + (size_t)s2 * DIM))[lane];
        half4 v3 = ((const half4*)(h + (size_t)s3 * DIM))[lane];
        a0 += fmaxf((float)v0.x, 0.f) + fmaxf((float)v1.x, 0.f)
            + fmaxf((float)v2.x, 0.f) + fmaxf((float)v3.x, 0.f);
        a1 += fmaxf((float)v0.y, 0.f) + fmaxf((float)v1.y, 0.f)
            + fmaxf((float)v2.y, 0.f) + fmaxf((float)v3.y, 0.f);
        a2 += fmaxf((float)v0.z, 0.f) + fmaxf((float)v1.z, 0.f)
            + fmaxf((float)v2.z, 0.f) + fmaxf((float)v3.z, 0.f);
        a3 += fmaxf((float)v0.w, 0.f) + fmaxf((float)v1.w, 0.f)
            + fmaxf((float)v2.w, 0.f) + fmaxf((float)v3.w, 0.f);
    }
    for (; e < end; e++) {
        half4 v = ((const half4*)(h + (size_t)srcbuf[e] * DIM))[lane];
        a0 += fmaxf((float)v.x, 0.f); a1 += fmaxf((float)v.y, 0.f);
        a2 += fmaxf((float)v.z, 0.f); a3 += fmaxf((float)v.w, 0.f);
    }
    half4 o;
    o.x = (_Float16)a0; o.y = (_Float16)a1;
    o.z = (_Float16)a2; o.w = (_Float16)a3;
    ((half4*)(z + (size_t)node * DIM))[lane] = o;
}

// ---------------------------------------------------------------------------
// Layers 1..4 gather with fused BN2: h = relu(scale*C + shift) on the fly.
// ---------------------------------------------------------------------------
__global__ __launch_bounds__(256) void gather_bn(const _Float16* __restrict__ C,
                                                 const int* __restrict__ ptr,
                                                 const int* __restrict__ srcbuf,
                                                 _Float16* __restrict__ z,
                                                 const float* __restrict__ scsh,
                                                 const float* __restrict__ eps,
                                                 int l) {
    int node = blockIdx.x * 4 + (threadIdx.x >> 6);
    if (node >= N_NODES) return;
    int lane = threadIdx.x & 63;
    float4 sc = ((const float4*)scsh)[lane];
    float4 sh = ((const float4*)(scsh + DIM))[lane];
    int beg = ptr[node], end = ptr[node + 1];
    float s = 1.0f + eps[l];
    half4 hv = ((const half4*)(C + (size_t)node * DIM))[lane];
    float a0 = s * fmaxf((float)hv.x * sc.x + sh.x, 0.f);
    float a1 = s * fmaxf((float)hv.y * sc.y + sh.y, 0.f);
    float a2 = s * fmaxf((float)hv.z * sc.z + sh.z, 0.f);
    float a3 = s * fmaxf((float)hv.w * sc.w + sh.w, 0.f);
    int e = beg;
    for (; e + 4 <= end; e += 4) {
        int s0 = srcbuf[e], s1 = srcbuf[e + 1], s2 = srcbuf[e + 2], s3 = srcbuf[e + 3];
        half4 v0 = ((const half4*)(C + (size_t)s0 * DIM))[lane];
        half4 v1 = ((const half4*)(C + (size_t)s1 * DIM))[lane];
        half4 v2 = ((const half4*)(C + (size_t)s2 * DIM))[lane];
        half4 v3 = ((const half4*)(C + (size_t)s3 * DIM))[lane];
        a0 += fmaxf((float)v0.x * sc.x + sh.x, 0.f) + fmaxf((float)v1.x * sc.x + sh.x, 0.f)
            + fmaxf((float)v2.x * sc.x + sh.x, 0.f) + fmaxf((float)v3.x * sc.x + sh.x, 0.f);
        a1 += fmaxf((float)v0.y * sc.y + sh.y, 0.f) + fmaxf((float)v1.y * sc.y + sh.y, 0.f)
            + fmaxf((float)v2.y * sc.y + sh.y, 0.f) + fmaxf((float)v3.y * sc.y + sh.y, 0.f);
        a2 += fmaxf((float)v0.z * sc.z + sh.z, 0.f) + fmaxf((float)v1.z * sc.z + sh.z, 0.f)
            + fmaxf((float)v2.z * sc.z + sh.z, 0.f) + fmaxf((float)v3.z * sc.z + sh.z, 0.f);
        a3 += fmaxf((float)v0.w * sc.w + sh.w, 0.f) + fmaxf((float)v1.w * sc.w + sh.w, 0.f)
            + fmaxf((float)v2.w * sc.w + sh.w, 0.f) + fmaxf((float)v3.w * sc.w + sh.w, 0.f);
    }
    for (; e < end; e++) {
        half4 v = ((const half4*)(C + (size_t)srcbuf[e] * DIM))[lane];
        a0 += fmaxf((float)v.x * sc.x + sh.x, 0.f);
        a1 += fmaxf((float)v.y * sc.y + sh.y, 0.f);
        a2 += fmaxf((float)v.z * sc.z + sh.z, 0.f);
        a3 += fmaxf((float)v.w * sc.w + sh.w, 0.f);
    }
    half4 o;
    o.x = (_Float16)a0; o.y = (_Float16)a1;
    o.z = (_Float16)a2; o.w = (_Float16)a3;
    ((half4*)(z + (size_t)node * DIM))[lane] = o;
}

// ===========================================================================
// GEMM: 128x128 tile, BK=128, XOR-swizzled LDS staging (unchanged from r7).
// NEW EPILOGUE: (1) C-tile staged to LDS (stride 136 halves, 16B-aligned
// rows) then stored coalesced as uint4 (1KB per wave-instr); (2) column
// stats go to 8-way replicated global buffers (stats + (by&7)*512) to cut
// per-address atomic contention 391 -> ~49.
// ===========================================================================
#define GEMM_EPILOGUE                                                        \
    __syncthreads();                                                         \
    float* colsum = (float*)((char*)smem + 49152);                           \
    float* colsq = colsum + 128;                                             \
    if (tid < 128) { colsum[tid] = 0.0f; colsq[tid] = 0.0f; }                \
    _Float16* Cs = (_Float16*)smem;                                          \
    float bcol[4];                                                           \
    _Pragma("unroll")                                                        \
    for (int j = 0; j < 4; j++) bcol[j] = bias[col0 + wn + j * 16 + lrow];   \
    float csum[4] = {0.f, 0.f, 0.f, 0.f};                                    \
    float csq[4] = {0.f, 0.f, 0.f, 0.f};                                     \
    _Pragma("unroll")                                                        \
    for (int i = 0; i < 4; i++) {                                            \
        int rl = wm + i * 16 + quad * 4;                                     \
        _Pragma("unroll")                                                    \
        for (int j = 0; j < 4; j++) {                                        \
            int cl = wn + j * 16 + lrow;                                     \
            _Pragma("unroll")                                                \
            for (int r = 0; r < 4; r++) {                                    \
                float v = acc[i][j][r] + bcol[j];                            \
                Cs[(rl + r) * 136 + cl] = (_Float16)v;                       \
                if (row0 + rl + r < M) { csum[j] += v; csq[j] += v * v; }    \
            }                                                                \
        }                                                                    \
    }                                                                        \
    __syncthreads();                                                         \
    {                                                                        \
        int rgrp = lane >> 4, ch = lane & 15;                                \
        _Pragma("unroll")                                                    \
        for (int it = 0; it < 8; it++) {                                     \
            int row = wid * 32 + it * 4 + rgrp;                              \
            uint4 vv = *(const uint4*)(Cs + row * 136 + ch * 8);             \
            *(uint4*)(C + (size_t)(row0 + row) * DIM + col0 + ch * 8) = vv;  \
        }                                                                    \
    }                                                                        \
    _Pragma("unroll")                                                        \
    for (int j = 0; j < 4; j++) {                                            \
        atomicAdd(&colsum[wn + j * 16 + lrow], csum[j]);                     \
        atomicAdd(&colsq[wn + j * 16 + lrow], csq[j]);                       \
    }                                                                        \
    __syncthreads();                                                         \
    if (tid < 128) {                                                         \
        float* st = stats + (blockIdx.y & 7) * 512;                          \
        atomicAdd(&st[col0 + tid], colsum[tid]);                             \
        atomicAdd(&st[DIM + col0 + tid], colsq[tid]);                        \
    }

__global__ __launch_bounds__(256) void gemm_f16(const _Float16* __restrict__ A,
                                                const _Float16* __restrict__ Wt,
                                                const float* __restrict__ bias,
                                                _Float16* __restrict__ C,
                                                float* __restrict__ stats,
                                                int M) {
    __shared__ uint4 smem[4096];  // 64 KB: A-tile 32K | B-tile 32K

    int tid = threadIdx.x;
    int wid = tid >> 6, lane = tid & 63;
    int quad = lane >> 4, lrow = lane & 15;
    int row0 = blockIdx.y * 128, col0 = blockIdx.x * 128;
    int wm = (wid & 1) * 64, wn = (wid >> 1) * 64;

    f32x4 acc[4][4] = {};
    const char* Ab = (const char*)A;
    const char* Bb = (const char*)Wt;

#pragma unroll
    for (int ko = 0; ko < 2; ko++) {
        int kb0 = ko * 256;  // byte offset of this K-half within a 512B row
#pragma unroll
        for (int j = 0; j < 8; j++) {
            int sbase = wid * 512 + j * 64;   // 16B-slot base (wave-uniform)
            int s = sbase + lane;
            int m = s >> 4;
            int c = (s & 15) ^ (m & 7);
            size_t go = (size_t)(row0 + m) * 512 + kb0 + c * 16;
            async16(Ab + go, (char*)smem + sbase * 16);
            size_t gob = (size_t)(col0 + m) * 512 + kb0 + c * 16;
            async16(Bb + gob, (char*)smem + 32768 + sbase * 16);
        }
        __syncthreads();
#pragma unroll
        for (int kc = 0; kc < 4; kc++) {
            half8 af[4], bf[4];
#pragma unroll
            for (int t = 0; t < 4; t++) {
                int ma = wm + t * 16 + lrow;
                int ca = kc * 4 + quad;
                af[t] = *(const half8*)((const char*)smem +
                                        (ma * 16 + (ca ^ (ma & 7))) * 16);
                int mb = wn + t * 16 + lrow;
                bf[t] = *(const half8*)((const char*)smem + 32768 +
                                        (mb * 16 + (ca ^ (mb & 7))) * 16);
            }
#pragma unroll
            for (int i = 0; i < 4; i++)
#pragma unroll
                for (int j2 = 0; j2 < 4; j2++)
                    acc[i][j2] = __builtin_amdgcn_mfma_f32_16x16x32_f16(
                        af[i], bf[j2], acc[i][j2], 0, 0, 0);
        }
        if (ko == 0) __syncthreads();
    }

    GEMM_EPILOGUE
}

// Same GEMM with fused input BN1+ReLU (scale/shift held in registers).
__global__ __launch_bounds__(256) void gemm_bn(const _Float16* __restrict__ A,
                                               const _Float16* __restrict__ Wt,
                                               const float* __restrict__ bias,
                                               const float* __restrict__ scsh,
                                               _Float16* __restrict__ C,
                                               float* __restrict__ stats,
                                               int M) {
    __shared__ uint4 smem[4096];  // 64 KB

    int tid = threadIdx.x;
    int wid = tid >> 6, lane = tid & 63;
    int quad = lane >> 4, lrow = lane & 15;
    int row0 = blockIdx.y * 128, col0 = blockIdx.x * 128;
    int wm = (wid & 1) * 64, wn = (wid >> 1) * 64;

    // Per-lane BN1 scale/shift fragments for all 8 k-chunks (fp16, regs)
    half8 scv[8], shv[8];
#pragma unroll
    for (int cc = 0; cc < 8; cc++) {
        int kk = cc * 32 + quad * 8;
        float4 s0 = *(const float4*)(scsh + kk);
        float4 s1 = *(const float4*)(scsh + kk + 4);
        float4 h0 = *(const float4*)(scsh + DIM + kk);
        float4 h1 = *(const float4*)(scsh + DIM + kk + 4);
        half8 sv = {(_Float16)s0.x, (_Float16)s0.y, (_Float16)s0.z, (_Float16)s0.w,
                    (_Float16)s1.x, (_Float16)s1.y, (_Float16)s1.z, (_Float16)s1.w};
        half8 hv = {(_Float16)h0.x, (_Float16)h0.y, (_Float16)h0.z, (_Float16)h0.w,
                    (_Float16)h1.x, (_Float16)h1.y, (_Float16)h1.z, (_Float16)h1.w};
        scv[cc] = sv;
        shv[cc] = hv;
    }

    f32x4 acc[4][4] = {};
    const char* Ab = (const char*)A;
    const char* Bb = (const char*)Wt;
    const half8 zerov = {0, 0, 0, 0, 0, 0, 0, 0};

#pragma unroll
    for (int ko = 0; ko < 2; ko++) {
        int kb0 = ko * 256;
#pragma unroll
        for (int j = 0; j < 8; j++) {
            int sbase = wid * 512 + j * 64;
            int s = sbase + lane;
            int m = s >> 4;
            int c = (s & 15) ^ (m & 7);
            size_t go = (size_t)(row0 + m) * 512 + kb0 + c * 16;
            async16(Ab + go, (char*)smem + sbase * 16);
            size_t gob = (size_t)(col0 + m) * 512 + kb0 + c * 16;
            async16(Bb + gob, (char*)smem + 32768 + sbase * 16);
        }
        __syncthreads();
#pragma unroll
        for (int kc = 0; kc < 4; kc++) {
            half8 af[4], bf[4];
            half8 sv = scv[ko * 4 + kc];
            half8 hv = shv[ko * 4 + kc];
#pragma unroll
            for (int t = 0; t < 4; t++) {
                int ma = wm + t * 16 + lrow;
                int ca = kc * 4 + quad;
                half8 a = *(const half8*)((const char*)smem +
                                          (ma * 16 + (ca ^ (ma & 7))) * 16);
                af[t] = __builtin_elementwise_max(a * sv + hv, zerov);
                int mb = wn + t * 16 + lrow;
                bf[t] = *(const half8*)((const char*)smem + 32768 +
                                        (mb * 16 + (ca ^ (mb & 7))) * 16);
            }
#pragma unroll
            for (int i = 0; i < 4; i++)
#pragma unroll
                for (int j2 = 0; j2 < 4; j2++)
                    acc[i][j2] = __builtin_amdgcn_mfma_f32_16x16x32_f16(
                        af[i], bf[j2], acc[i][j2], 0, 0, 0);
        }
        if (ko == 0) __syncthreads();
    }

    GEMM_EPILOGUE
}

// ---------------------------------------------------------------------------
// Finalize BN from 8 replicated stat buffers; zeroes them for reuse.
// ---------------------------------------------------------------------------
__global__ __launch_bounds__(256) void bn_finalize(float* __restrict__ stats,
                                                   const float* __restrict__ g,
                                                   const float* __restrict__ beta,
                                                   float* __restrict__ scsh,
                                                   int n) {
    int d = threadIdx.x;
    float s = 0.0f, sq = 0.0f;
#pragma unroll
    for (int r = 0; r < 8; r++) {
        s += stats[r * 512 + d];
        sq += stats[r * 512 + 256 + d];
        stats[r * 512 + d] = 0.0f;
        stats[r * 512 + 256 + d] = 0.0f;
    }
    float invn = 1.0f / (float)n;
    float mean = s * invn;
    float var = sq * invn - mean * mean;
    float inv = rsqrtf(var + 1e-5f);
    float scale = g[d] * inv;
    scsh[d] = scale;
    scsh[DIM + d] = beta[d] - mean * scale;
}

// ---------------------------------------------------------------------------
// Final BN apply (layer 4): no relu, fp32 out.
// ---------------------------------------------------------------------------
__global__ __launch_bounds__(256) void bn_apply_f(const _Float16* __restrict__ in,
                                                  float* __restrict__ outf,
                                                  const float* __restrict__ scsh) {
    size_t i = (size_t)blockIdx.x * 256 + threadIdx.x;
    int c4 = (int)(i & 63);
    float4 sc = ((const float4*)scsh)[c4];
    float4 sh = ((const float4*)(scsh + DIM))[c4];
    half4 v = ((const half4*)in)[i];
    float4 o;
    o.x = (float)v.x * sc.x + sh.x;
    o.y = (float)v.y * sc.y + sh.y;
    o.z = (float)v.z * sc.z + sh.z;
    o.w = (float)v.w * sc.w + sh.w;
    ((float4*)outf)[i] = o;
}

// ---------------------------------------------------------------------------
extern "C" void kernel_launch(void* const* d_in, const int* in_sizes, int n_in,
                              void* d_out, int out_size, void* d_ws, size_t ws_size,
                              hipStream_t stream) {
    (void)in_sizes; (void)n_in; (void)out_size; (void)ws_size;
    const float* x   = (const float*)d_in[0];
    const int*   src = (const int*)d_in[1];
    const int*   dst = (const int*)d_in[2];
    const float* W1  = (const float*)d_in[3];
    const float* b1  = (const float*)d_in[4];
    const float* g1  = (const float*)d_in[5];
    const float* bt1 = (const float*)d_in[6];
    const float* W2  = (const float*)d_in[7];
    const float* b2  = (const float*)d_in[8];
    const float* eps = (const float*)d_in[9];
    const float* bng = (const float*)d_in[10];
    const float* bnb = (const float*)d_in[11];
    float* out = (float*)d_out;

    const int N = N_NODES, E = N_EDGES, D = DIM;
    size_t NDp = (size_t)MPAD * D;

    _Float16* gin  = (_Float16*)d_ws;              // gather output / GEMM1 in
    _Float16* C1   = gin + NDp;                    // GEMM1 raw out (also xh @ l0)
    _Float16* C2   = C1 + NDp;                     // GEMM2 raw out
    _Float16* Wt   = C2 + NDp;                     // 10 * 256*256 fp16
    float* statsA = (float*)(Wt + 10 * 65536);     // 8 * 512 f (BN1 replicas)
    float* statsB = statsA + 4096;                 // 8 * 512 f (BN2 replicas)
    float* scshA = statsB + 4096;                  // 512 f (BN1)
    float* scshB = scshA + 512;                    // 512 f (BN2)
    int* deg     = (int*)(scshB + 512);            // N (cursor)
    int* ptr     = deg + N;                        // N+1
    int* bsum    = ptr + N + 1;                    // 64
    int* srcbuf  = bsum + 64;                      // E

    const int ELEM4_BLOCKS = N * D / 4 / 256;      // 12500
    const int NODE_BLOCKS  = (N + 3) / 4;          // 12500
    const int E_BLOCKS     = (E + 255) / 256;      // 1172
    const int SCAN_BLOCKS  = (N + 1023) / 1024;    // 49
    const dim3 GEMM_GRID(2, MPAD / 128);           // (2, 391)

    // ---- One-time per call: CSR build, stats zero, conversions ----
    hipMemsetAsync(deg, 0, N * sizeof(int), stream);
    hipMemsetAsync(statsA, 0, 8192 * sizeof(float), stream);
    hist_dst<<<E_BLOCKS, 256, 0, stream>>>(dst, deg, E);
    scan_blk<<<SCAN_BLOCKS, 1024, 0, stream>>>(deg, ptr, bsum, N);
    scan_top<<<1, 64, 0, stream>>>(bsum, ptr, SCAN_BLOCKS, N, E);
    scan_add<<<SCAN_BLOCKS, 1024, 0, stream>>>(ptr, bsum, deg, N);
    scatter_src<<<E_BLOCKS, 256, 0, stream>>>(src, dst, deg, srcbuf, E);
    wconv<<<160, 256, 0, stream>>>(W1, W2, Wt);
    x2h<<<ELEM4_BLOCKS, 256, 0, stream>>>(x, C1);  // C1 = xh for layer 0

    for (int l = 0; l < 5; l++) {
        // Gather (+ fused BN2-of-previous-layer for l>=1) -> gin (fp16)
        if (l == 0)
            gather_h<<<NODE_BLOCKS, 256, 0, stream>>>(C1, ptr, srcbuf, gin, eps);
        else
            gather_bn<<<NODE_BLOCKS, 256, 0, stream>>>(C2, ptr, srcbuf, gin,
                                                       scshB, eps, l);

        // C1 = gin @ W1 + b1 (raw), fused BN1 stats
        gemm_f16<<<GEMM_GRID, 256, 0, stream>>>(
            gin, Wt + (size_t)l * 65536, b1 + (size_t)l * D, C1, statsA, N);
        bn_finalize<<<1, 256, 0, stream>>>(statsA, g1 + (size_t)l * D,
                                           bt1 + (size_t)l * D, scshA, N);

        // C2 = relu(BN1(C1)) @ W2 + b2 (raw), fused BN2 stats
        gemm_bn<<<GEMM_GRID, 256, 0, stream>>>(
            C1, Wt + (size_t)(5 + l) * 65536, b2 + (size_t)l * D, scshA,
            C2, statsB, N);
        bn_finalize<<<1, 256, 0, stream>>>(statsB, bng + (size_t)l * D,
                                           bnb + (size_t)l * D, scshB, N);

        // BN2 consumed fused in next layer's gather; final layer writes out.
        if (l == 4)
            bn_apply_f<<<ELEM4_BLOCKS, 256, 0, stream>>>(C2, out, scshB);
    }
}